// Round 22
// baseline (1213.830 us; speedup 1.0000x reference)
//
#include <hip/hip_runtime.h>
#include <hip/hip_bf16.h>

typedef __attribute__((ext_vector_type(8))) short short8;
typedef __attribute__((ext_vector_type(4))) float floatx4;
typedef __attribute__((ext_vector_type(8))) int intx8;
typedef __attribute__((ext_vector_type(4))) int intx4;

#define S_LEN  50
#define BATCH  128
#define DIM    512
#define HID    512
#define G3     1536
#define VOCAB  30000
#define TOKENS 6400
#define NB256  118      // ceil(30000/256) vocab chunks in decode
#define NVC    472      // partial columns = NB256 * 4 waves
#define NWG    (25 * NB256)   // 2950 decode blocks

__device__ __forceinline__ float bf2f(short u) {
    union { unsigned int i; float f; } c;
    c.i = ((unsigned int)(unsigned short)u) << 16;
    return c.f;
}
__device__ __forceinline__ unsigned short f2bf(float x) {
    __hip_bfloat16 h = __float2bfloat16(x);
    unsigned short u;
    __builtin_memcpy(&u, &h, 2);
    return u;
}
// f32 -> OCP e4m3fn, RNE, with subnormals; clamps to +-448; never emits NaN byte.
__device__ __forceinline__ unsigned char f2e4m3(float x) {
    union { float f; unsigned u; } v; v.f = x;
    unsigned s = (v.u >> 24) & 0x80u;
    v.u &= 0x7FFFFFFFu;
    if (v.f >= 464.f) return (unsigned char)(s | 0x7E);
    if (v.f < 0.015625f) {                       // subnormal: units of 2^-9
        int q = (int)rintf(v.f * 512.f);         // 0..8 (8 -> 0x08 = 2^-6 normal)
        return (unsigned char)(s | (unsigned)q);
    }
    unsigned lsb = (v.u >> 20) & 1u;
    v.u += 0x7FFFFu + lsb;                       // RNE at bit 20
    unsigned e8 = ((v.u >> 23) & 0xFFu) - 120u;  // fp8 biased exponent
    unsigned m3 = (v.u >> 20) & 7u;
    return (unsigned char)(s | (e8 << 3) | m3);
}
__device__ __forceinline__ float e4m32f(unsigned b) {
    unsigned s = b & 0x80u, e = (b >> 3) & 0xFu, m = b & 7u;
    if (e == 0) { float f = (float)m * 0.001953125f; return s ? -f : f; }
    union { unsigned u; float f; } v;
    v.u = (s << 24) | ((e + 120u) << 23) | (m << 20);
    return v.f;
}
__device__ __forceinline__ void gl_lds16(const void* g, void* l) {
    __builtin_amdgcn_global_load_lds(
        (const __attribute__((address_space(1))) void*)g,
        (__attribute__((address_space(3))) void*)l, 16, 0, 0);
}

// ---------------- f32 -> bf16 bulk convert (8 elems/thread) ----------------
__global__ void k_cvt_bf16(const float* __restrict__ src,
                           unsigned short* __restrict__ dst, int n8) {
    int g = blockIdx.x * 256 + threadIdx.x;
    if (g >= n8) return;
    const float* s = src + (size_t)g * 8;
    union { short8 v; unsigned short u[8]; } o;
#pragma unroll
    for (int i = 0; i < 8; ++i) o.u[i] = f2bf(s[i]);
    *(short8*)(dst + (size_t)g * 8) = o.v;
}

// ---------------- f32 -> fp8 e4m3 bulk convert (16 elems/thread) ----------------
__global__ void k_cvt_fp8(const float* __restrict__ src,
                          unsigned char* __restrict__ dst, int n16) {
    int g = blockIdx.x * 256 + threadIdx.x;
    if (g >= n16) return;
    const float* s = src + (size_t)g * 16;
    union { uint4 v; unsigned char b[16]; } o;
#pragma unroll
    for (int i = 0; i < 16; ++i) o.b[i] = f2e4m3(s[i]);
    *(uint4*)(dst + (size_t)g * 16) = o.v;
}

// ---------------- bf16 -> fp8 e4m3 bulk convert (16 elems/thread) ----------------
__global__ void k_hs8(const unsigned short* __restrict__ src,
                      unsigned char* __restrict__ dst, int n16) {
    int g = blockIdx.x * 256 + threadIdx.x;
    if (g >= n16) return;
    const unsigned short* s = src + (size_t)g * 16;
    union { uint4 v; unsigned char b[16]; } o;
#pragma unroll
    for (int i = 0; i < 16; ++i) o.b[i] = f2e4m3(bf2f((short)s[i]));
    *(uint4*)(dst + (size_t)g * 16) = o.v;
}

// ---------------- embedding gather + convert: X[token][512] bf16 ----------------
__global__ void k_gather_x(const float* __restrict__ emb, const int* __restrict__ idx,
                           unsigned short* __restrict__ X) {
    int g = blockIdx.x * 256 + threadIdx.x;   // 8-elem group; total TOKENS*DIM/8
    int token = g >> 6;                       // 64 groups per token
    int chunk = (g & 63) << 3;
    const float* src = emb + (size_t)idx[token] * DIM + chunk;
    union { short8 v; unsigned short u[8]; } o;
#pragma unroll
    for (int i = 0; i < 8; ++i) o.u[i] = f2bf(src[i]);
    *(short8*)(X + (size_t)token * DIM + chunk) = o.v;
}

// ---------------- GI = X @ W_ih^T + b_ih   [6400 x 1536] fp32 ----------------
__launch_bounds__(256)
__global__ void k_gemm_gi(const unsigned short* __restrict__ X,
                          const unsigned short* __restrict__ Wih,
                          const float* __restrict__ b_ih,
                          float* __restrict__ GI) {
    __shared__ unsigned short As[64][72];
    __shared__ unsigned short Bs[64][72];
    int m0 = blockIdx.x * 64;
    int n0 = blockIdx.y * 64;
    int t = threadIdx.x;
    int w = t >> 6, lane = t & 63;
    floatx4 zero = {0.f, 0.f, 0.f, 0.f};
    floatx4 acc[4];
#pragma unroll
    for (int i = 0; i < 4; ++i) acc[i] = zero;
    int srow = t >> 2, scol = (t & 3) * 16;
    for (int k0 = 0; k0 < DIM; k0 += 64) {
        *(short8*)&As[srow][scol]     = *(const short8*)(X   + (size_t)(m0 + srow) * DIM + k0 + scol);
        *(short8*)&As[srow][scol + 8] = *(const short8*)(X   + (size_t)(m0 + srow) * DIM + k0 + scol + 8);
        *(short8*)&Bs[srow][scol]     = *(const short8*)(Wih + (size_t)(n0 + srow) * DIM + k0 + scol);
        *(short8*)&Bs[srow][scol + 8] = *(const short8*)(Wih + (size_t)(n0 + srow) * DIM + k0 + scol + 8);
        __syncthreads();
#pragma unroll
        for (int kt = 0; kt < 2; ++kt) {
            short8 a = *(const short8*)&As[w * 16 + (lane & 15)][kt * 32 + (lane >> 4) * 8];
#pragma unroll
            for (int nt = 0; nt < 4; ++nt) {
                short8 b = *(const short8*)&Bs[nt * 16 + (lane & 15)][kt * 32 + (lane >> 4) * 8];
                acc[nt] = __builtin_amdgcn_mfma_f32_16x16x32_bf16(a, b, acc[nt], 0, 0, 0);
            }
        }
        __syncthreads();
    }
#pragma unroll
    for (int nt = 0; nt < 4; ++nt)
#pragma unroll
        for (int r = 0; r < 4; ++r) {
            int row = m0 + w * 16 + (lane >> 4) * 4 + r;
            int col = n0 + nt * 16 + (lane & 15);
            GI[(size_t)row * G3 + col] = acc[nt][r] + b_ih[col];
        }
}

// ---------------- GRU single step: 256 blocks x 64 thr (all CUs) ----------------
__launch_bounds__(64)
__global__ void k_gru_step(const float* __restrict__ GI,
                           const unsigned short* __restrict__ Whh,
                           const float* __restrict__ b_hh,
                           float* __restrict__ hf,
                           const unsigned short* __restrict__ hin,
                           unsigned short* __restrict__ hout,
                           int s) {
    int lane = threadIdx.x & 63;
    int bg = blockIdx.x & 7;      // batch group (8 groups of 16)
    int hs = blockIdx.x >> 3;     // hidden slice (32 slices of 16)
    int jc = hs * 16 + (lane & 15);   // hidden unit (N index)

    const unsigned short* pa  = hin + (size_t)(bg * 16 + (lane & 15)) * HID + (lane >> 4) * 8;
    const unsigned short* pb0 = Whh + (size_t)(0 * HID + jc) * DIM + (lane >> 4) * 8;
    const unsigned short* pb1 = Whh + (size_t)(1 * HID + jc) * DIM + (lane >> 4) * 8;
    const unsigned short* pb2 = Whh + (size_t)(2 * HID + jc) * DIM + (lane >> 4) * 8;

    floatx4 acc0 = {0.f, 0.f, 0.f, 0.f};
    floatx4 acc1 = {0.f, 0.f, 0.f, 0.f};
    floatx4 acc2 = {0.f, 0.f, 0.f, 0.f};
#pragma unroll
    for (int kt = 0; kt < 16; ++kt) {
        short8 a = *(const short8*)(pa + kt * 32);
        acc0 = __builtin_amdgcn_mfma_f32_16x16x32_bf16(a, *(const short8*)(pb0 + kt * 32), acc0, 0, 0, 0);
        acc1 = __builtin_amdgcn_mfma_f32_16x16x32_bf16(a, *(const short8*)(pb1 + kt * 32), acc1, 0, 0, 0);
        acc2 = __builtin_amdgcn_mfma_f32_16x16x32_bf16(a, *(const short8*)(pb2 + kt * 32), acc2, 0, 0, 0);
    }
    float bhr = b_hh[jc], bhz = b_hh[jc + 512], bhn = b_hh[jc + 1024];
#pragma unroll
    for (int r = 0; r < 4; ++r) {
        int brow = bg * 16 + (lane >> 4) * 4 + r;   // batch row (M index)
        int tok = s * BATCH + brow;
        const float* gi = GI + (size_t)tok * G3;
        float rg = 1.f / (1.f + __expf(-(gi[jc] + acc0[r] + bhr)));
        float zg = 1.f / (1.f + __expf(-(gi[jc + 512] + acc1[r] + bhz)));
        float ng = tanhf(gi[jc + 1024] + rg * (acc2[r] + bhn));
        size_t hidx = (size_t)brow * HID + jc;
        float hn = (1.f - zg) * ng + zg * hf[hidx];
        hf[hidx] = hn;
        hout[hidx] = f2bf(hn);
    }
}

// ---------------- decode: MX-fp8, 256x256 tile, counted-vmcnt global_load_lds ----------------
// R14 schedule; fp8 K-tiles of 128 (4 iters), same 128-B LDS row geometry.
// 16 waves (4x4), 64x64/wave, mfma_scale_f32_16x16x128_f8f6f4, unit scales.
// VGPR budget fix vs R21: process B-fragments in PAIRS (bf[2] live, not bf[4])
// so peak live = acc 64 + bf 16 + af 8 + offsets ~30 <= 128 (no scratch spill).
__launch_bounds__(1024, 4)
__global__ void k_decode(const unsigned char* __restrict__ HS8,
                         const unsigned char* __restrict__ W8,
                         const float* __restrict__ b_out,
                         float* __restrict__ partial) {
    __shared__ unsigned char As[2][32768];
    __shared__ unsigned char Bs[2][32768];

    // bijective XCD chunk swizzle (nwg=2950, q=368, r=6)
    int bid = blockIdx.x;
    int xcd = bid & 7, pos = bid >> 3;
    int p = (xcd < 6 ? xcd * 369 : 2214 + (xcd - 6) * 368) + pos;
    // supergroup order: 14 groups of 8 nb + 1 group of 6 nb; mb-major within group
    int sgrp = p / 200;
    int rr   = p - sgrp * 200;
    int mb, nb;
    if (sgrp < 14) { mb = rr >> 3; nb = sgrp * 8 + (rr & 7); }
    else           { int q6 = rr / 6; mb = q6; nb = 112 + (rr - q6 * 6); }
    int m0 = mb * 256, n0 = nb * 256;

    int t = threadIdx.x, w = t >> 6, lane = t & 63;
    int wr = w >> 2, wc = w & 3;            // 4x4 wave grid

    floatx4 zero = {0.f, 0.f, 0.f, 0.f};
    floatx4 acc[4][4];
#pragma unroll
    for (int mi = 0; mi < 4; ++mi)
#pragma unroll
        for (int ni = 0; ni < 4; ++ni) acc[mi][ni] = zero;

    // staging: each wave stages two 8-row chunks (1 KB = 8 rows x 128 B) of A and B.
    // Linear LDS dest (chunk*1024 + lane*16); swizzle via pre-swizzled global src:
    // content at LDS byte d of row r = global byte (d&127) ^ ((r&7)<<4).
    int r8  = lane >> 3;
    int cbs = ((lane & 7) ^ r8) * 16;
    int c0 = w * 2, c1 = c0 + 1;
    int rA0 = c0 * 8 + r8, rA1 = c1 * 8 + r8;
    const unsigned char* gA0 = HS8 + (size_t)(m0 + rA0) * DIM + cbs;
    const unsigned char* gA1 = HS8 + (size_t)(m0 + rA1) * DIM + cbs;
    int v0 = n0 + rA0; if (v0 > VOCAB - 1) v0 = VOCAB - 1;
    int v1 = n0 + rA1; if (v1 > VOCAB - 1) v1 = VOCAB - 1;
    const unsigned char* gB0 = W8 + (size_t)v0 * DIM + cbs;
    const unsigned char* gB1 = W8 + (size_t)v1 * DIM + cbs;

    // swizzled read offsets (bytes): lane reads its 32-byte k-chunk as two 16B halves
    int roA[4][2], roB[4][2];
#pragma unroll
    for (int mi = 0; mi < 4; ++mi)
#pragma unroll
        for (int h = 0; h < 2; ++h) {
            int row = wr * 64 + mi * 16 + (lane & 15);
            roA[mi][h] = (row * 128 + (lane >> 4) * 32 + h * 16) ^ ((row & 7) << 4);
        }
#pragma unroll
    for (int ni = 0; ni < 4; ++ni)
#pragma unroll
        for (int h = 0; h < 2; ++h) {
            int row = wc * 64 + ni * 16 + (lane & 15);
            roB[ni][h] = (row * 128 + (lane >> 4) * 32 + h * 16) ^ ((row & 7) << 4);
        }

#define STAGE(kt, buf) do { int ko_ = (kt) * 128;                        \
        gl_lds16(gA0 + ko_, (char*)As[buf] + c0 * 1024);                 \
        gl_lds16(gA1 + ko_, (char*)As[buf] + c1 * 1024);                 \
        gl_lds16(gB0 + ko_, (char*)Bs[buf] + c0 * 1024);                 \
        gl_lds16(gB1 + ko_, (char*)Bs[buf] + c1 * 1024); } while (0)

    STAGE(0, 0);
    __builtin_amdgcn_sched_barrier(0);

    for (int kt = 0; kt < 4; ++kt) {
        int cur = kt & 1;
        if (kt < 3) {
            STAGE(kt + 1, cur ^ 1);
            __builtin_amdgcn_sched_barrier(0);
            asm volatile("s_waitcnt vmcnt(4)" ::: "memory");   // tile kt landed; kt+1 in flight
        } else {
            asm volatile("s_waitcnt vmcnt(0)" ::: "memory");
        }
        __builtin_amdgcn_sched_barrier(0);
        __builtin_amdgcn_s_barrier();
        __builtin_amdgcn_sched_barrier(0);
        // pair-split: only 2 B-fragments live at once (VGPR cap 128, no spill)
#pragma unroll
        for (int pr = 0; pr < 2; ++pr) {
            intx8 bf[2];
#pragma unroll
            for (int nj = 0; nj < 2; ++nj) {
                int ni = pr * 2 + nj;
                intx4 lo = *(const intx4*)((const char*)Bs[cur] + roB[ni][0]);
                intx4 hi = *(const intx4*)((const char*)Bs[cur] + roB[ni][1]);
                bf[nj] = __builtin_shufflevector(lo, hi, 0, 1, 2, 3, 4, 5, 6, 7);
            }
#pragma unroll
            for (int mi = 0; mi < 4; ++mi) {
                intx4 lo = *(const intx4*)((const char*)As[cur] + roA[mi][0]);
                intx4 hi = *(const intx4*)((const char*)As[cur] + roA[mi][1]);
                intx8 af = __builtin_shufflevector(lo, hi, 0, 1, 2, 3, 4, 5, 6, 7);
                acc[mi][pr * 2]     = __builtin_amdgcn_mfma_scale_f32_16x16x128_f8f6f4(
                    af, bf[0], acc[mi][pr * 2],     0, 0, 0, 0x7F7F7F7F, 0, 0x7F7F7F7F);
                acc[mi][pr * 2 + 1] = __builtin_amdgcn_mfma_scale_f32_16x16x128_f8f6f4(
                    af, bf[1], acc[mi][pr * 2 + 1], 0, 0, 0, 0x7F7F7F7F, 0, 0x7F7F7F7F);
            }
        }
        __builtin_amdgcn_sched_barrier(0);
        __builtin_amdgcn_s_barrier();
        __builtin_amdgcn_sched_barrier(0);
    }
#undef STAGE

    // epilogue: exp + per-token partial sums over this wave's 64 vocab cols
    float esum[4][4];   // [mi][r]
#pragma unroll
    for (int mi = 0; mi < 4; ++mi)
#pragma unroll
        for (int r = 0; r < 4; ++r) esum[mi][r] = 0.f;
#pragma unroll
    for (int ni = 0; ni < 4; ++ni) {
        int v = n0 + wc * 64 + ni * 16 + (lane & 15);
        bool ok = v < VOCAB;
        float bo = ok ? b_out[v] : 0.f;
#pragma unroll
        for (int mi = 0; mi < 4; ++mi)
#pragma unroll
            for (int r = 0; r < 4; ++r) {
                float logit = acc[mi][ni][r] + bo;
                esum[mi][r] += ok ? __expf(logit) : 0.f;
            }
    }
#pragma unroll
    for (int d = 1; d < 16; d <<= 1)
#pragma unroll
        for (int mi = 0; mi < 4; ++mi)
#pragma unroll
            for (int r = 0; r < 4; ++r) esum[mi][r] += __shfl_xor(esum[mi][r], d, 64);
    if ((lane & 15) == 0) {
#pragma unroll
        for (int mi = 0; mi < 4; ++mi)
#pragma unroll
            for (int r = 0; r < 4; ++r) {
                int tok = m0 + wr * 64 + mi * 16 + (lane >> 4) * 4 + r;
                partial[(size_t)tok * 512 + nb * 4 + wc] = esum[mi][r];
            }
    }
}

// ---------------- fixed-order reduce of partials -> lse ----------------
__global__ void k_reduce_lse(const float* __restrict__ partial, float* __restrict__ lse) {
    int tok = blockIdx.x * 4 + (threadIdx.x >> 6);
    int lane = threadIdx.x & 63;
    float s = 0.f;
    for (int j = lane; j < NVC; j += 64) s += partial[(size_t)tok * 512 + j];
#pragma unroll
    for (int d = 1; d < 64; d <<= 1) s += __shfl_xor(s, d, 64);
    if (lane == 0) lse[tok] = logf(s);
}

// ---------------- target logit (fp8 data): one wave per token ----------------
__global__ void k_tlogit(const unsigned char* __restrict__ HS8,
                         const unsigned char* __restrict__ W8,
                         const float* __restrict__ b_out,
                         const int* __restrict__ target,
                         float* __restrict__ tlg) {
    int tok = blockIdx.x * 4 + (threadIdx.x >> 6);
    int lane = threadIdx.x & 63;
    int tg = target[tok];
    uint2 ha = *(const uint2*)(HS8 + (size_t)tok * DIM + lane * 8);
    uint2 wa = *(const uint2*)(W8 + (size_t)tg * DIM + lane * 8);
    float s = 0.f;
#pragma unroll
    for (int i = 0; i < 4; ++i)
        s += e4m32f((ha.x >> (8 * i)) & 0xFF) * e4m32f((wa.x >> (8 * i)) & 0xFF);
#pragma unroll
    for (int i = 0; i < 4; ++i)
        s += e4m32f((ha.y >> (8 * i)) & 0xFF) * e4m32f((wa.y >> (8 * i)) & 0xFF);
#pragma unroll
    for (int d = 1; d < 64; d <<= 1) s += __shfl_xor(s, d, 64);
    if (lane == 0) tlg[tok] = s + b_out[tg];
}

// ---------------- loss + masked mean ----------------
__global__ void k_finalize(const float* __restrict__ lse, const float* __restrict__ tlg,
                           const int* __restrict__ target, float* __restrict__ out) {
    __shared__ float ssum[256];
    __shared__ float scnt[256];
    int t = threadIdx.x;
    float ls = 0.f, lc = 0.f;
    for (int i = t; i < TOKENS; i += 256) {
        int tg = target[i];
        float loss = (tg != 0) ? (lse[i] - tlg[i]) : 0.f;
        out[i] = loss;
        ls += loss;
        lc += (tg != 0) ? 1.f : 0.f;
    }
    ssum[t] = ls; scnt[t] = lc;
    __syncthreads();
    for (int d = 128; d > 0; d >>= 1) {
        if (t < d) { ssum[t] += ssum[t + d]; scnt[t] += scnt[t + d]; }
        __syncthreads();
    }
    if (t == 0) out[TOKENS] = ssum[0] / fmaxf(scnt[0], 1.f);
}

extern "C" void kernel_launch(void* const* d_in, const int* in_sizes, int n_in,
                              void* d_out, int out_size, void* d_ws, size_t ws_size,
                              hipStream_t stream) {
    const int*   review_input  = (const int*)d_in[2];
    const int*   review_target = (const int*)d_in[3];
    const float* word_emb      = (const float*)d_in[4];
    const float* W_ih          = (const float*)d_in[5];
    const float* W_hh          = (const float*)d_in[6];
    const float* b_ih          = (const float*)d_in[7];
    const float* b_hh          = (const float*)d_in[8];
    const float* W_out         = (const float*)d_in[9];
    const float* b_out         = (const float*)d_in[10];
    float* out = (float*)d_out;

    char* ws = (char*)d_ws;
    size_t off = 0;
    auto alloc = [&](size_t n) { char* p = ws + off; off += (n + 255) & ~(size_t)255; return p; };
    unsigned short* Xb    = (unsigned short*)alloc((size_t)TOKENS * DIM * 2);
    unsigned short* Wihb  = (unsigned short*)alloc((size_t)G3 * DIM * 2);
    unsigned short* Whhb  = (unsigned short*)alloc((size_t)G3 * HID * 2);
    unsigned char*  Wout8 = (unsigned char*)alloc((size_t)VOCAB * DIM);
    unsigned short* HS    = (unsigned short*)alloc((size_t)TOKENS * HID * 2);
    unsigned char*  HS8   = (unsigned char*)alloc((size_t)TOKENS * HID);
    unsigned short* hzero = (unsigned short*)alloc((size_t)BATCH * HID * 2);
    float* hf      = (float*)alloc((size_t)BATCH * HID * 4);
    float* GI      = (float*)alloc((size_t)TOKENS * G3 * 4);
    float* partial = (float*)alloc((size_t)TOKENS * 512 * 4);
    float* lse     = (float*)alloc((size_t)TOKENS * 4);
    float* tlg     = (float*)alloc((size_t)TOKENS * 4);
    (void)ws_size; (void)in_sizes; (void)n_in; (void)out_size;

    // weight conversions + embedding gather
    k_cvt_bf16<<<dim3((G3 * DIM / 8 + 255) / 256), dim3(256), 0, stream>>>(W_ih, Wihb, G3 * DIM / 8);
    k_cvt_bf16<<<dim3((G3 * HID / 8 + 255) / 256), dim3(256), 0, stream>>>(W_hh, Whhb, G3 * HID / 8);
    k_cvt_fp8<<<dim3((VOCAB * DIM / 16 + 255) / 256), dim3(256), 0, stream>>>(W_out, Wout8, VOCAB * DIM / 16);
    k_gather_x<<<dim3(TOKENS * DIM / 8 / 256), dim3(256), 0, stream>>>(word_emb, review_input, Xb);

    // GI = X @ W_ih^T + b_ih
    k_gemm_gi<<<dim3(TOKENS / 64, G3 / 64), dim3(256), 0, stream>>>(Xb, Wihb, b_ih, GI);

    // GRU recurrence: 50 per-step kernels, 256 blocks x 64 thr (all CUs)
    hipMemsetAsync(hf, 0, (size_t)BATCH * HID * 4, stream);
    hipMemsetAsync(hzero, 0, (size_t)BATCH * HID * 2, stream);
    for (int s = 0; s < S_LEN; ++s) {
        const unsigned short* hin = s ? (HS + (size_t)(s - 1) * BATCH * HID) : hzero;
        unsigned short* hout = HS + (size_t)s * BATCH * HID;
        k_gru_step<<<dim3(256), dim3(64), 0, stream>>>(GI, Whhb, b_hh, hf, hin, hout, s);
    }
    // HS bf16 -> fp8 for decode
    k_hs8<<<dim3((TOKENS * HID / 16 + 255) / 256), dim3(256), 0, stream>>>(HS, HS8, TOKENS * HID / 16);

    // decode: partial exp-sums, reduce to lse, target logits, final loss
    k_decode<<<dim3(NWG), dim3(1024), 0, stream>>>(HS8, Wout8, b_out, partial);
    k_reduce_lse<<<dim3(TOKENS / 4), dim3(256), 0, stream>>>(partial, lse);
    k_tlogit<<<dim3(TOKENS / 4), dim3(256), 0, stream>>>(HS8, Wout8, b_out, review_target, tlg);
    k_finalize<<<dim3(1), dim3(256), 0, stream>>>(lse, tlg, review_target, out);
}

// Round 23
// 536.380 us; speedup vs baseline: 2.2630x; 2.2630x over previous
//
#include <hip/hip_runtime.h>
#include <hip/hip_bf16.h>

typedef __attribute__((ext_vector_type(8))) short short8;
typedef __attribute__((ext_vector_type(4))) float floatx4;

#define S_LEN  50
#define BATCH  128
#define DIM    512
#define HID    512
#define G3     1536
#define VOCAB  30000
#define TOKENS 6400
#define NB256  118      // ceil(30000/256) vocab chunks in decode
#define NVC    472      // partial columns = NB256 * 4 waves
#define NWG    (25 * NB256)   // 2950 decode blocks

__device__ __forceinline__ float bf2f(short u) {
    union { unsigned int i; float f; } c;
    c.i = ((unsigned int)(unsigned short)u) << 16;
    return c.f;
}
__device__ __forceinline__ unsigned short f2bf(float x) {
    __hip_bfloat16 h = __float2bfloat16(x);
    unsigned short u;
    __builtin_memcpy(&u, &h, 2);
    return u;
}
// f32 -> OCP e4m3fn, RNE, with subnormals; clamps to +-448; never emits NaN byte.
__device__ __forceinline__ unsigned char f2e4m3(float x) {
    union { float f; unsigned u; } v; v.f = x;
    unsigned s = (v.u >> 24) & 0x80u;
    v.u &= 0x7FFFFFFFu;
    if (v.f >= 464.f) return (unsigned char)(s | 0x7E);
    if (v.f < 0.015625f) {                       // subnormal: units of 2^-9
        int q = (int)rintf(v.f * 512.f);         // 0..8 (8 -> 0x08 = 2^-6 normal)
        return (unsigned char)(s | (unsigned)q);
    }
    unsigned lsb = (v.u >> 20) & 1u;
    v.u += 0x7FFFFu + lsb;                       // RNE at bit 20
    unsigned e8 = ((v.u >> 23) & 0xFFu) - 120u;  // fp8 biased exponent
    unsigned m3 = (v.u >> 20) & 7u;
    return (unsigned char)(s | (e8 << 3) | m3);
}
__device__ __forceinline__ float e4m32f(unsigned b) {
    unsigned s = b & 0x80u, e = (b >> 3) & 0xFu, m = b & 7u;
    if (e == 0) { float f = (float)m * 0.001953125f; return s ? -f : f; }
    union { unsigned u; float f; } v;
    v.u = (s << 24) | ((e + 120u) << 23) | (m << 20);
    return v.f;
}
__device__ __forceinline__ void gl_lds16(const void* g, void* l) {
    __builtin_amdgcn_global_load_lds(
        (const __attribute__((address_space(1))) void*)g,
        (__attribute__((address_space(3))) void*)l, 16, 0, 0);
}

// ---------------- f32 -> bf16 bulk convert (8 elems/thread) ----------------
__global__ void k_cvt_bf16(const float* __restrict__ src,
                           unsigned short* __restrict__ dst, int n8) {
    int g = blockIdx.x * 256 + threadIdx.x;
    if (g >= n8) return;
    const float* s = src + (size_t)g * 8;
    union { short8 v; unsigned short u[8]; } o;
#pragma unroll
    for (int i = 0; i < 8; ++i) o.u[i] = f2bf(s[i]);
    *(short8*)(dst + (size_t)g * 8) = o.v;
}

// ---------------- f32 -> fp8 e4m3 bulk convert (16 elems/thread) ----------------
__global__ void k_cvt_fp8(const float* __restrict__ src,
                          unsigned char* __restrict__ dst, int n16) {
    int g = blockIdx.x * 256 + threadIdx.x;
    if (g >= n16) return;
    const float* s = src + (size_t)g * 16;
    union { uint4 v; unsigned char b[16]; } o;
#pragma unroll
    for (int i = 0; i < 16; ++i) o.b[i] = f2e4m3(s[i]);
    *(uint4*)(dst + (size_t)g * 16) = o.v;
}

// ---------------- bf16 -> fp8 e4m3 bulk convert (16 elems/thread) ----------------
__global__ void k_hs8(const unsigned short* __restrict__ src,
                      unsigned char* __restrict__ dst, int n16) {
    int g = blockIdx.x * 256 + threadIdx.x;
    if (g >= n16) return;
    const unsigned short* s = src + (size_t)g * 16;
    union { uint4 v; unsigned char b[16]; } o;
#pragma unroll
    for (int i = 0; i < 16; ++i) o.b[i] = f2e4m3(bf2f((short)s[i]));
    *(uint4*)(dst + (size_t)g * 16) = o.v;
}

// ---------------- embedding gather + convert: X[token][512] bf16 ----------------
__global__ void k_gather_x(const float* __restrict__ emb, const int* __restrict__ idx,
                           unsigned short* __restrict__ X) {
    int g = blockIdx.x * 256 + threadIdx.x;   // 8-elem group; total TOKENS*DIM/8
    int token = g >> 6;                       // 64 groups per token
    int chunk = (g & 63) << 3;
    const float* src = emb + (size_t)idx[token] * DIM + chunk;
    union { short8 v; unsigned short u[8]; } o;
#pragma unroll
    for (int i = 0; i < 8; ++i) o.u[i] = f2bf(src[i]);
    *(short8*)(X + (size_t)token * DIM + chunk) = o.v;
}

// ---------------- GI = X @ W_ih^T + b_ih   [6400 x 1536] fp32 ----------------
__launch_bounds__(256)
__global__ void k_gemm_gi(const unsigned short* __restrict__ X,
                          const unsigned short* __restrict__ Wih,
                          const float* __restrict__ b_ih,
                          float* __restrict__ GI) {
    __shared__ unsigned short As[64][72];
    __shared__ unsigned short Bs[64][72];
    int m0 = blockIdx.x * 64;
    int n0 = blockIdx.y * 64;
    int t = threadIdx.x;
    int w = t >> 6, lane = t & 63;
    floatx4 zero = {0.f, 0.f, 0.f, 0.f};
    floatx4 acc[4];
#pragma unroll
    for (int i = 0; i < 4; ++i) acc[i] = zero;
    int srow = t >> 2, scol = (t & 3) * 16;
    for (int k0 = 0; k0 < DIM; k0 += 64) {
        *(short8*)&As[srow][scol]     = *(const short8*)(X   + (size_t)(m0 + srow) * DIM + k0 + scol);
        *(short8*)&As[srow][scol + 8] = *(const short8*)(X   + (size_t)(m0 + srow) * DIM + k0 + scol + 8);
        *(short8*)&Bs[srow][scol]     = *(const short8*)(Wih + (size_t)(n0 + srow) * DIM + k0 + scol);
        *(short8*)&Bs[srow][scol + 8] = *(const short8*)(Wih + (size_t)(n0 + srow) * DIM + k0 + scol + 8);
        __syncthreads();
#pragma unroll
        for (int kt = 0; kt < 2; ++kt) {
            short8 a = *(const short8*)&As[w * 16 + (lane & 15)][kt * 32 + (lane >> 4) * 8];
#pragma unroll
            for (int nt = 0; nt < 4; ++nt) {
                short8 b = *(const short8*)&Bs[nt * 16 + (lane & 15)][kt * 32 + (lane >> 4) * 8];
                acc[nt] = __builtin_amdgcn_mfma_f32_16x16x32_bf16(a, b, acc[nt], 0, 0, 0);
            }
        }
        __syncthreads();
    }
#pragma unroll
    for (int nt = 0; nt < 4; ++nt)
#pragma unroll
        for (int r = 0; r < 4; ++r) {
            int row = m0 + w * 16 + (lane >> 4) * 4 + r;
            int col = n0 + nt * 16 + (lane & 15);
            GI[(size_t)row * G3 + col] = acc[nt][r] + b_ih[col];
        }
}

// ---------------- GRU single step: 256 blocks x 64 thr (all CUs) ----------------
__launch_bounds__(64)
__global__ void k_gru_step(const float* __restrict__ GI,
                           const unsigned short* __restrict__ Whh,
                           const float* __restrict__ b_hh,
                           float* __restrict__ hf,
                           const unsigned short* __restrict__ hin,
                           unsigned short* __restrict__ hout,
                           int s) {
    int lane = threadIdx.x & 63;
    int bg = blockIdx.x & 7;      // batch group (8 groups of 16)
    int hs = blockIdx.x >> 3;     // hidden slice (32 slices of 16)
    int jc = hs * 16 + (lane & 15);   // hidden unit (N index)

    const unsigned short* pa  = hin + (size_t)(bg * 16 + (lane & 15)) * HID + (lane >> 4) * 8;
    const unsigned short* pb0 = Whh + (size_t)(0 * HID + jc) * DIM + (lane >> 4) * 8;
    const unsigned short* pb1 = Whh + (size_t)(1 * HID + jc) * DIM + (lane >> 4) * 8;
    const unsigned short* pb2 = Whh + (size_t)(2 * HID + jc) * DIM + (lane >> 4) * 8;

    floatx4 acc0 = {0.f, 0.f, 0.f, 0.f};
    floatx4 acc1 = {0.f, 0.f, 0.f, 0.f};
    floatx4 acc2 = {0.f, 0.f, 0.f, 0.f};
#pragma unroll
    for (int kt = 0; kt < 16; ++kt) {
        short8 a = *(const short8*)(pa + kt * 32);
        acc0 = __builtin_amdgcn_mfma_f32_16x16x32_bf16(a, *(const short8*)(pb0 + kt * 32), acc0, 0, 0, 0);
        acc1 = __builtin_amdgcn_mfma_f32_16x16x32_bf16(a, *(const short8*)(pb1 + kt * 32), acc1, 0, 0, 0);
        acc2 = __builtin_amdgcn_mfma_f32_16x16x32_bf16(a, *(const short8*)(pb2 + kt * 32), acc2, 0, 0, 0);
    }
    float bhr = b_hh[jc], bhz = b_hh[jc + 512], bhn = b_hh[jc + 1024];
#pragma unroll
    for (int r = 0; r < 4; ++r) {
        int brow = bg * 16 + (lane >> 4) * 4 + r;   // batch row (M index)
        int tok = s * BATCH + brow;
        const float* gi = GI + (size_t)tok * G3;
        float rg = 1.f / (1.f + __expf(-(gi[jc] + acc0[r] + bhr)));
        float zg = 1.f / (1.f + __expf(-(gi[jc + 512] + acc1[r] + bhz)));
        float ng = tanhf(gi[jc + 1024] + rg * (acc2[r] + bhn));
        size_t hidx = (size_t)brow * HID + jc;
        float hn = (1.f - zg) * ng + zg * hf[hidx];
        hf[hidx] = hn;
        hout[hidx] = f2bf(hn);
    }
}

// ---------------- decode: fp8 non-scaled MFMA, 256x256 tile, counted-vmcnt ----------------
// R14 schedule; fp8 K-tiles of 128 (4 iters), same 128-B LDS row geometry as the
// proven bf16 config. 16 waves (4x4), 64x64/wave. mfma_f32_16x16x32_fp8_fp8:
// i64 operands (2 VGPRs, single ds_read_b64) -> register pressure BELOW bf16.
// C/D layout identical to bf16 16x16x32 -> epilogue unchanged.
__launch_bounds__(1024, 4)
__global__ void k_decode(const unsigned char* __restrict__ HS8,
                         const unsigned char* __restrict__ W8,
                         const float* __restrict__ b_out,
                         float* __restrict__ partial) {
    __shared__ unsigned char As[2][32768];
    __shared__ unsigned char Bs[2][32768];

    // bijective XCD chunk swizzle (nwg=2950, q=368, r=6)
    int bid = blockIdx.x;
    int xcd = bid & 7, pos = bid >> 3;
    int p = (xcd < 6 ? xcd * 369 : 2214 + (xcd - 6) * 368) + pos;
    // supergroup order: 14 groups of 8 nb + 1 group of 6 nb; mb-major within group
    int sgrp = p / 200;
    int rr   = p - sgrp * 200;
    int mb, nb;
    if (sgrp < 14) { mb = rr >> 3; nb = sgrp * 8 + (rr & 7); }
    else           { int q6 = rr / 6; mb = q6; nb = 112 + (rr - q6 * 6); }
    int m0 = mb * 256, n0 = nb * 256;

    int t = threadIdx.x, w = t >> 6, lane = t & 63;
    int wr = w >> 2, wc = w & 3;            // 4x4 wave grid

    floatx4 zero = {0.f, 0.f, 0.f, 0.f};
    floatx4 acc[4][4];
#pragma unroll
    for (int mi = 0; mi < 4; ++mi)
#pragma unroll
        for (int ni = 0; ni < 4; ++ni) acc[mi][ni] = zero;

    // staging: each wave stages two 8-row chunks (1 KB = 8 rows x 128 B) of A and B.
    // Linear LDS dest (chunk*1024 + lane*16); swizzle via pre-swizzled global src:
    // content at LDS byte d of row r = global byte (d&127) ^ ((r&7)<<4).
    int r8  = lane >> 3;
    int cbs = ((lane & 7) ^ r8) * 16;
    int c0 = w * 2, c1 = c0 + 1;
    int rA0 = c0 * 8 + r8, rA1 = c1 * 8 + r8;
    const unsigned char* gA0 = HS8 + (size_t)(m0 + rA0) * DIM + cbs;
    const unsigned char* gA1 = HS8 + (size_t)(m0 + rA1) * DIM + cbs;
    int v0 = n0 + rA0; if (v0 > VOCAB - 1) v0 = VOCAB - 1;
    int v1 = n0 + rA1; if (v1 > VOCAB - 1) v1 = VOCAB - 1;
    const unsigned char* gB0 = W8 + (size_t)v0 * DIM + cbs;
    const unsigned char* gB1 = W8 + (size_t)v1 * DIM + cbs;

    // per-fragment row bases and swizzle keys (offset = base + ((kh*32|g8) ^ swz))
    int g8 = (lane >> 4) * 8;               // lane's 8-byte k-group within 32-B span
    int pA[4], sA[4], pB[4], sB[4];
#pragma unroll
    for (int mi = 0; mi < 4; ++mi) {
        int row = wr * 64 + mi * 16 + (lane & 15);
        pA[mi] = row * 128;
        sA[mi] = (row & 7) << 4;
    }
#pragma unroll
    for (int ni = 0; ni < 4; ++ni) {
        int row = wc * 64 + ni * 16 + (lane & 15);
        pB[ni] = row * 128;
        sB[ni] = (row & 7) << 4;
    }

#define STAGE(kt, buf) do { int ko_ = (kt) * 128;                        \
        gl_lds16(gA0 + ko_, (char*)As[buf] + c0 * 1024);                 \
        gl_lds16(gA1 + ko_, (char*)As[buf] + c1 * 1024);                 \
        gl_lds16(gB0 + ko_, (char*)Bs[buf] + c0 * 1024);                 \
        gl_lds16(gB1 + ko_, (char*)Bs[buf] + c1 * 1024); } while (0)

    STAGE(0, 0);
    __builtin_amdgcn_sched_barrier(0);

    for (int kt = 0; kt < 4; ++kt) {
        int cur = kt & 1;
        if (kt < 3) {
            STAGE(kt + 1, cur ^ 1);
            __builtin_amdgcn_sched_barrier(0);
            asm volatile("s_waitcnt vmcnt(4)" ::: "memory");   // tile kt landed; kt+1 in flight
        } else {
            asm volatile("s_waitcnt vmcnt(0)" ::: "memory");
        }
        __builtin_amdgcn_sched_barrier(0);
        __builtin_amdgcn_s_barrier();
        __builtin_amdgcn_sched_barrier(0);
#pragma unroll
        for (int kh = 0; kh < 4; ++kh) {
            long long af[4], bf[4];
#pragma unroll
            for (int mi = 0; mi < 4; ++mi)
                af[mi] = *(const long long*)((const char*)As[cur] + pA[mi] + (((kh * 32) | g8) ^ sA[mi]));
#pragma unroll
            for (int ni = 0; ni < 4; ++ni)
                bf[ni] = *(const long long*)((const char*)Bs[cur] + pB[ni] + (((kh * 32) | g8) ^ sB[ni]));
#pragma unroll
            for (int mi = 0; mi < 4; ++mi)
#pragma unroll
                for (int ni = 0; ni < 4; ++ni)
                    acc[mi][ni] = __builtin_amdgcn_mfma_f32_16x16x32_fp8_fp8(
                        af[mi], bf[ni], acc[mi][ni], 0, 0, 0);
        }
        __builtin_amdgcn_sched_barrier(0);
        __builtin_amdgcn_s_barrier();
        __builtin_amdgcn_sched_barrier(0);
    }
#undef STAGE

    // epilogue: exp + per-token partial sums over this wave's 64 vocab cols
    float esum[4][4];   // [mi][r]
#pragma unroll
    for (int mi = 0; mi < 4; ++mi)
#pragma unroll
        for (int r = 0; r < 4; ++r) esum[mi][r] = 0.f;
#pragma unroll
    for (int ni = 0; ni < 4; ++ni) {
        int v = n0 + wc * 64 + ni * 16 + (lane & 15);
        bool ok = v < VOCAB;
        float bo = ok ? b_out[v] : 0.f;
#pragma unroll
        for (int mi = 0; mi < 4; ++mi)
#pragma unroll
            for (int r = 0; r < 4; ++r) {
                float logit = acc[mi][ni][r] + bo;
                esum[mi][r] += ok ? __expf(logit) : 0.f;
            }
    }
#pragma unroll
    for (int d = 1; d < 16; d <<= 1)
#pragma unroll
        for (int mi = 0; mi < 4; ++mi)
#pragma unroll
            for (int r = 0; r < 4; ++r) esum[mi][r] += __shfl_xor(esum[mi][r], d, 64);
    if ((lane & 15) == 0) {
#pragma unroll
        for (int mi = 0; mi < 4; ++mi)
#pragma unroll
            for (int r = 0; r < 4; ++r) {
                int tok = m0 + wr * 64 + mi * 16 + (lane >> 4) * 4 + r;
                partial[(size_t)tok * 512 + nb * 4 + wc] = esum[mi][r];
            }
    }
}

// ---------------- fixed-order reduce of partials -> lse ----------------
__global__ void k_reduce_lse(const float* __restrict__ partial, float* __restrict__ lse) {
    int tok = blockIdx.x * 4 + (threadIdx.x >> 6);
    int lane = threadIdx.x & 63;
    float s = 0.f;
    for (int j = lane; j < NVC; j += 64) s += partial[(size_t)tok * 512 + j];
#pragma unroll
    for (int d = 1; d < 64; d <<= 1) s += __shfl_xor(s, d, 64);
    if (lane == 0) lse[tok] = logf(s);
}

// ---------------- target logit (fp8 data): one wave per token ----------------
__global__ void k_tlogit(const unsigned char* __restrict__ HS8,
                         const unsigned char* __restrict__ W8,
                         const float* __restrict__ b_out,
                         const int* __restrict__ target,
                         float* __restrict__ tlg) {
    int tok = blockIdx.x * 4 + (threadIdx.x >> 6);
    int lane = threadIdx.x & 63;
    int tg = target[tok];
    uint2 ha = *(const uint2*)(HS8 + (size_t)tok * DIM + lane * 8);
    uint2 wa = *(const uint2*)(W8 + (size_t)tg * DIM + lane * 8);
    float s = 0.f;
#pragma unroll
    for (int i = 0; i < 4; ++i)
        s += e4m32f((ha.x >> (8 * i)) & 0xFF) * e4m32f((wa.x >> (8 * i)) & 0xFF);
#pragma unroll
    for (int i = 0; i < 4; ++i)
        s += e4m32f((ha.y >> (8 * i)) & 0xFF) * e4m32f((wa.y >> (8 * i)) & 0xFF);
#pragma unroll
    for (int d = 1; d < 64; d <<= 1) s += __shfl_xor(s, d, 64);
    if (lane == 0) tlg[tok] = s + b_out[tg];
}

// ---------------- loss + masked mean ----------------
__global__ void k_finalize(const float* __restrict__ lse, const float* __restrict__ tlg,
                           const int* __restrict__ target, float* __restrict__ out) {
    __shared__ float ssum[256];
    __shared__ float scnt[256];
    int t = threadIdx.x;
    float ls = 0.f, lc = 0.f;
    for (int i = t; i < TOKENS; i += 256) {
        int tg = target[i];
        float loss = (tg != 0) ? (lse[i] - tlg[i]) : 0.f;
        out[i] = loss;
        ls += loss;
        lc += (tg != 0) ? 1.f : 0.f;
    }
    ssum[t] = ls; scnt[t] = lc;
    __syncthreads();
    for (int d = 128; d > 0; d >>= 1) {
        if (t < d) { ssum[t] += ssum[t + d]; scnt[t] += scnt[t + d]; }
        __syncthreads();
    }
    if (t == 0) out[TOKENS] = ssum[0] / fmaxf(scnt[0], 1.f);
}

extern "C" void kernel_launch(void* const* d_in, const int* in_sizes, int n_in,
                              void* d_out, int out_size, void* d_ws, size_t ws_size,
                              hipStream_t stream) {
    const int*   review_input  = (const int*)d_in[2];
    const int*   review_target = (const int*)d_in[3];
    const float* word_emb      = (const float*)d_in[4];
    const float* W_ih          = (const float*)d_in[5];
    const float* W_hh          = (const float*)d_in[6];
    const float* b_ih          = (const float*)d_in[7];
    const float* b_hh          = (const float*)d_in[8];
    const float* W_out         = (const float*)d_in[9];
    const float* b_out         = (const float*)d_in[10];
    float* out = (float*)d_out;

    char* ws = (char*)d_ws;
    size_t off = 0;
    auto alloc = [&](size_t n) { char* p = ws + off; off += (n + 255) & ~(size_t)255; return p; };
    unsigned short* Xb    = (unsigned short*)alloc((size_t)TOKENS * DIM * 2);
    unsigned short* Wihb  = (unsigned short*)alloc((size_t)G3 * DIM * 2);
    unsigned short* Whhb  = (unsigned short*)alloc((size_t)G3 * HID * 2);
    unsigned char*  Wout8 = (unsigned char*)alloc((size_t)VOCAB * DIM);
    unsigned short* HS    = (unsigned short*)alloc((size_t)TOKENS * HID * 2);
    unsigned char*  HS8   = (unsigned char*)alloc((size_t)TOKENS * HID);
    unsigned short* hzero = (unsigned short*)alloc((size_t)BATCH * HID * 2);
    float* hf      = (float*)alloc((size_t)BATCH * HID * 4);
    float* GI      = (float*)alloc((size_t)TOKENS * G3 * 4);
    float* partial = (float*)alloc((size_t)TOKENS * 512 * 4);
    float* lse     = (float*)alloc((size_t)TOKENS * 4);
    float* tlg     = (float*)alloc((size_t)TOKENS * 4);
    (void)ws_size; (void)in_sizes; (void)n_in; (void)out_size;

    // weight conversions + embedding gather
    k_cvt_bf16<<<dim3((G3 * DIM / 8 + 255) / 256), dim3(256), 0, stream>>>(W_ih, Wihb, G3 * DIM / 8);
    k_cvt_bf16<<<dim3((G3 * HID / 8 + 255) / 256), dim3(256), 0, stream>>>(W_hh, Whhb, G3 * HID / 8);
    k_cvt_fp8<<<dim3((VOCAB * DIM / 16 + 255) / 256), dim3(256), 0, stream>>>(W_out, Wout8, VOCAB * DIM / 16);
    k_gather_x<<<dim3(TOKENS * DIM / 8 / 256), dim3(256), 0, stream>>>(word_emb, review_input, Xb);

    // GI = X @ W_ih^T + b_ih
    k_gemm_gi<<<dim3(TOKENS / 64, G3 / 64), dim3(256), 0, stream>>>(Xb, Wihb, b_ih, GI);

    // GRU recurrence: 50 per-step kernels, 256 blocks x 64 thr (all CUs)
    hipMemsetAsync(hf, 0, (size_t)BATCH * HID * 4, stream);
    hipMemsetAsync(hzero, 0, (size_t)BATCH * HID * 2, stream);
    for (int s = 0; s < S_LEN; ++s) {
        const unsigned short* hin = s ? (HS + (size_t)(s - 1) * BATCH * HID) : hzero;
        unsigned short* hout = HS + (size_t)s * BATCH * HID;
        k_gru_step<<<dim3(256), dim3(64), 0, stream>>>(GI, Whhb, b_hh, hf, hin, hout, s);
    }
    // HS bf16 -> fp8 for decode
    k_hs8<<<dim3((TOKENS * HID / 16 + 255) / 256), dim3(256), 0, stream>>>(HS, HS8, TOKENS * HID / 16);

    // decode: partial exp-sums, reduce to lse, target logits, final loss
    k_decode<<<dim3(NWG), dim3(1024), 0, stream>>>(HS8, Wout8, b_out, partial);
    k_reduce_lse<<<dim3(TOKENS / 4), dim3(256), 0, stream>>>(partial, lse);
    k_tlogit<<<dim3(TOKENS / 4), dim3(256), 0, stream>>>(HS8, Wout8, b_out, review_target, tlg);
    k_finalize<<<dim3(1), dim3(256), 0, stream>>>(lse, tlg, review_target, out);
}

// Round 24
// 505.730 us; speedup vs baseline: 2.4002x; 1.0606x over previous
//
#include <hip/hip_runtime.h>
#include <hip/hip_bf16.h>

typedef __attribute__((ext_vector_type(8))) short short8;
typedef __attribute__((ext_vector_type(4))) float floatx4;

#define S_LEN  50
#define BATCH  128
#define DIM    512
#define HID    512
#define G3     1536
#define VOCAB  30000
#define TOKENS 6400
#define NB256  118      // ceil(30000/256) vocab chunks in decode
#define NVC    472      // partial columns = NB256 * 4 waves
#define NWG    (25 * NB256)   // 2950 decode blocks

__device__ __forceinline__ float bf2f(short u) {
    union { unsigned int i; float f; } c;
    c.i = ((unsigned int)(unsigned short)u) << 16;
    return c.f;
}
__device__ __forceinline__ unsigned short f2bf(float x) {
    __hip_bfloat16 h = __float2bfloat16(x);
    unsigned short u;
    __builtin_memcpy(&u, &h, 2);
    return u;
}
// f32 -> OCP e4m3fn, RNE, branchless (selects only). Clamps to +-448, no NaN byte.
__device__ __forceinline__ unsigned char f2e4m3(float x) {
    union { float f; unsigned u; } v; v.f = x;
    unsigned s = (v.u >> 24) & 0x80u;
    v.u &= 0x7FFFFFFFu;
    float af = fminf(v.f, 448.f);              // clamp (also kills inf)
    // normal-path encode (valid when af >= 2^-6)
    union { float f; unsigned u; } w; w.f = af;
    unsigned lsb = (w.u >> 20) & 1u;
    unsigned wr  = w.u + 0x7FFFFu + lsb;       // RNE at bit 20
    unsigned nrm = (((wr >> 23) & 0xFFu) - 120u) * 8u + ((wr >> 20) & 7u);
    // subnormal-path encode (units of 2^-9, RNE via rintf)
    unsigned sub = (unsigned)(int)rintf(af * 512.f);
    unsigned mag = (af < 0.015625f) ? sub : nrm;
    return (unsigned char)(s | mag);
}
__device__ __forceinline__ float e4m32f(unsigned b) {
    unsigned s = b & 0x80u, e = (b >> 3) & 0xFu, m = b & 7u;
    float fs = (float)m * 0.001953125f;
    union { unsigned u; float f; } v;
    v.u = ((e + 120u) << 23) | (m << 20);
    float mag = (e == 0) ? fs : v.f;
    return s ? -mag : mag;
}
__device__ __forceinline__ void gl_lds16(const void* g, void* l) {
    __builtin_amdgcn_global_load_lds(
        (const __attribute__((address_space(1))) void*)g,
        (__attribute__((address_space(3))) void*)l, 16, 0, 0);
}

// ---------------- f32 -> bf16 bulk convert (8 elems/thread) ----------------
__global__ void k_cvt_bf16(const float* __restrict__ src,
                           unsigned short* __restrict__ dst, int n8) {
    int g = blockIdx.x * 256 + threadIdx.x;
    if (g >= n8) return;
    const float* s = src + (size_t)g * 8;
    union { short8 v; unsigned short u[8]; } o;
#pragma unroll
    for (int i = 0; i < 8; ++i) o.u[i] = f2bf(s[i]);
    *(short8*)(dst + (size_t)g * 8) = o.v;
}

// ---------------- f32 -> fp8 e4m3 bulk convert (16 elems/thread) ----------------
__global__ void k_cvt_fp8(const float* __restrict__ src,
                          unsigned char* __restrict__ dst, int n16) {
    int g = blockIdx.x * 256 + threadIdx.x;
    if (g >= n16) return;
    const float* s = src + (size_t)g * 16;
    union { uint4 v; unsigned char b[16]; } o;
#pragma unroll
    for (int i = 0; i < 16; ++i) o.b[i] = f2e4m3(s[i]);
    *(uint4*)(dst + (size_t)g * 16) = o.v;
}

// ---------------- embedding gather + convert: X[token][512] bf16 ----------------
__global__ void k_gather_x(const float* __restrict__ emb, const int* __restrict__ idx,
                           unsigned short* __restrict__ X) {
    int g = blockIdx.x * 256 + threadIdx.x;   // 8-elem group; total TOKENS*DIM/8
    int token = g >> 6;                       // 64 groups per token
    int chunk = (g & 63) << 3;
    const float* src = emb + (size_t)idx[token] * DIM + chunk;
    union { short8 v; unsigned short u[8]; } o;
#pragma unroll
    for (int i = 0; i < 8; ++i) o.u[i] = f2bf(src[i]);
    *(short8*)(X + (size_t)token * DIM + chunk) = o.v;
}

// ---------------- GI = X @ W_ih^T + b_ih   [6400 x 1536] fp32 ----------------
__launch_bounds__(256)
__global__ void k_gemm_gi(const unsigned short* __restrict__ X,
                          const unsigned short* __restrict__ Wih,
                          const float* __restrict__ b_ih,
                          float* __restrict__ GI) {
    __shared__ unsigned short As[64][72];
    __shared__ unsigned short Bs[64][72];
    int m0 = blockIdx.x * 64;
    int n0 = blockIdx.y * 64;
    int t = threadIdx.x;
    int w = t >> 6, lane = t & 63;
    floatx4 zero = {0.f, 0.f, 0.f, 0.f};
    floatx4 acc[4];
#pragma unroll
    for (int i = 0; i < 4; ++i) acc[i] = zero;
    int srow = t >> 2, scol = (t & 3) * 16;
    for (int k0 = 0; k0 < DIM; k0 += 64) {
        *(short8*)&As[srow][scol]     = *(const short8*)(X   + (size_t)(m0 + srow) * DIM + k0 + scol);
        *(short8*)&As[srow][scol + 8] = *(const short8*)(X   + (size_t)(m0 + srow) * DIM + k0 + scol + 8);
        *(short8*)&Bs[srow][scol]     = *(const short8*)(Wih + (size_t)(n0 + srow) * DIM + k0 + scol);
        *(short8*)&Bs[srow][scol + 8] = *(const short8*)(Wih + (size_t)(n0 + srow) * DIM + k0 + scol + 8);
        __syncthreads();
#pragma unroll
        for (int kt = 0; kt < 2; ++kt) {
            short8 a = *(const short8*)&As[w * 16 + (lane & 15)][kt * 32 + (lane >> 4) * 8];
#pragma unroll
            for (int nt = 0; nt < 4; ++nt) {
                short8 b = *(const short8*)&Bs[nt * 16 + (lane & 15)][kt * 32 + (lane >> 4) * 8];
                acc[nt] = __builtin_amdgcn_mfma_f32_16x16x32_bf16(a, b, acc[nt], 0, 0, 0);
            }
        }
        __syncthreads();
    }
#pragma unroll
    for (int nt = 0; nt < 4; ++nt)
#pragma unroll
        for (int r = 0; r < 4; ++r) {
            int row = m0 + w * 16 + (lane >> 4) * 4 + r;
            int col = n0 + nt * 16 + (lane & 15);
            GI[(size_t)row * G3 + col] = acc[nt][r] + b_ih[col];
        }
}

// ---------------- GRU single step: 256 blocks x 64 thr (all CUs) ----------------
// Writes both bf16 h (for next step's MFMA A-operand) and fp8 h (for decode).
__launch_bounds__(64)
__global__ void k_gru_step(const float* __restrict__ GI,
                           const unsigned short* __restrict__ Whh,
                           const float* __restrict__ b_hh,
                           float* __restrict__ hf,
                           const unsigned short* __restrict__ hin,
                           unsigned short* __restrict__ hout,
                           unsigned char* __restrict__ hout8,
                           int s) {
    int lane = threadIdx.x & 63;
    int bg = blockIdx.x & 7;      // batch group (8 groups of 16)
    int hs = blockIdx.x >> 3;     // hidden slice (32 slices of 16)
    int jc = hs * 16 + (lane & 15);   // hidden unit (N index)

    const unsigned short* pa  = hin + (size_t)(bg * 16 + (lane & 15)) * HID + (lane >> 4) * 8;
    const unsigned short* pb0 = Whh + (size_t)(0 * HID + jc) * DIM + (lane >> 4) * 8;
    const unsigned short* pb1 = Whh + (size_t)(1 * HID + jc) * DIM + (lane >> 4) * 8;
    const unsigned short* pb2 = Whh + (size_t)(2 * HID + jc) * DIM + (lane >> 4) * 8;

    floatx4 acc0 = {0.f, 0.f, 0.f, 0.f};
    floatx4 acc1 = {0.f, 0.f, 0.f, 0.f};
    floatx4 acc2 = {0.f, 0.f, 0.f, 0.f};
#pragma unroll
    for (int kt = 0; kt < 16; ++kt) {
        short8 a = *(const short8*)(pa + kt * 32);
        acc0 = __builtin_amdgcn_mfma_f32_16x16x32_bf16(a, *(const short8*)(pb0 + kt * 32), acc0, 0, 0, 0);
        acc1 = __builtin_amdgcn_mfma_f32_16x16x32_bf16(a, *(const short8*)(pb1 + kt * 32), acc1, 0, 0, 0);
        acc2 = __builtin_amdgcn_mfma_f32_16x16x32_bf16(a, *(const short8*)(pb2 + kt * 32), acc2, 0, 0, 0);
    }
    float bhr = b_hh[jc], bhz = b_hh[jc + 512], bhn = b_hh[jc + 1024];
#pragma unroll
    for (int r = 0; r < 4; ++r) {
        int brow = bg * 16 + (lane >> 4) * 4 + r;   // batch row (M index)
        int tok = s * BATCH + brow;
        const float* gi = GI + (size_t)tok * G3;
        float rg = 1.f / (1.f + __expf(-(gi[jc] + acc0[r] + bhr)));
        float zg = 1.f / (1.f + __expf(-(gi[jc + 512] + acc1[r] + bhz)));
        float ng = tanhf(gi[jc + 1024] + rg * (acc2[r] + bhn));
        size_t hidx = (size_t)brow * HID + jc;
        float hn = (1.f - zg) * ng + zg * hf[hidx];
        hf[hidx] = hn;
        float hb = bf2f((short)f2bf(hn));          // decode sees fp8(bf16(h)) like R23
        hout[hidx] = f2bf(hn);
        hout8[hidx] = f2e4m3(hb);
    }
}

// ---------------- decode: fp8 non-scaled MFMA, 256x256 tile, counted-vmcnt ----------------
// R23-proven: 16 waves (4x4), 64x64/wave, fp8 K-tiles of 128 (4 iters),
// mfma_f32_16x16x32_fp8_fp8 with i64 operands (ds_read_b64), VGPR ~60, no spill.
__launch_bounds__(1024, 4)
__global__ void k_decode(const unsigned char* __restrict__ HS8,
                         const unsigned char* __restrict__ W8,
                         const float* __restrict__ b_out,
                         float* __restrict__ partial) {
    __shared__ unsigned char As[2][32768];
    __shared__ unsigned char Bs[2][32768];

    // bijective XCD chunk swizzle (nwg=2950, q=368, r=6)
    int bid = blockIdx.x;
    int xcd = bid & 7, pos = bid >> 3;
    int p = (xcd < 6 ? xcd * 369 : 2214 + (xcd - 6) * 368) + pos;
    // supergroup order: 14 groups of 8 nb + 1 group of 6 nb; mb-major within group
    int sgrp = p / 200;
    int rr   = p - sgrp * 200;
    int mb, nb;
    if (sgrp < 14) { mb = rr >> 3; nb = sgrp * 8 + (rr & 7); }
    else           { int q6 = rr / 6; mb = q6; nb = 112 + (rr - q6 * 6); }
    int m0 = mb * 256, n0 = nb * 256;

    int t = threadIdx.x, w = t >> 6, lane = t & 63;
    int wr = w >> 2, wc = w & 3;            // 4x4 wave grid

    floatx4 zero = {0.f, 0.f, 0.f, 0.f};
    floatx4 acc[4][4];
#pragma unroll
    for (int mi = 0; mi < 4; ++mi)
#pragma unroll
        for (int ni = 0; ni < 4; ++ni) acc[mi][ni] = zero;

    // staging: each wave stages two 8-row chunks (1 KB = 8 rows x 128 B) of A and B.
    // Linear LDS dest (chunk*1024 + lane*16); swizzle via pre-swizzled global src:
    // content at LDS byte d of row r = global byte (d&127) ^ ((r&7)<<4).
    int r8  = lane >> 3;
    int cbs = ((lane & 7) ^ r8) * 16;
    int c0 = w * 2, c1 = c0 + 1;
    int rA0 = c0 * 8 + r8, rA1 = c1 * 8 + r8;
    const unsigned char* gA0 = HS8 + (size_t)(m0 + rA0) * DIM + cbs;
    const unsigned char* gA1 = HS8 + (size_t)(m0 + rA1) * DIM + cbs;
    int v0 = n0 + rA0; if (v0 > VOCAB - 1) v0 = VOCAB - 1;
    int v1 = n0 + rA1; if (v1 > VOCAB - 1) v1 = VOCAB - 1;
    const unsigned char* gB0 = W8 + (size_t)v0 * DIM + cbs;
    const unsigned char* gB1 = W8 + (size_t)v1 * DIM + cbs;

    // per-fragment row bases and swizzle keys (offset = base + ((kh*32|g8) ^ swz))
    int g8 = (lane >> 4) * 8;               // lane's 8-byte k-group within 32-B span
    int pA[4], sA[4], pB[4], sB[4];
#pragma unroll
    for (int mi = 0; mi < 4; ++mi) {
        int row = wr * 64 + mi * 16 + (lane & 15);
        pA[mi] = row * 128;
        sA[mi] = (row & 7) << 4;
    }
#pragma unroll
    for (int ni = 0; ni < 4; ++ni) {
        int row = wc * 64 + ni * 16 + (lane & 15);
        pB[ni] = row * 128;
        sB[ni] = (row & 7) << 4;
    }

#define STAGE(kt, buf) do { int ko_ = (kt) * 128;                        \
        gl_lds16(gA0 + ko_, (char*)As[buf] + c0 * 1024);                 \
        gl_lds16(gA1 + ko_, (char*)As[buf] + c1 * 1024);                 \
        gl_lds16(gB0 + ko_, (char*)Bs[buf] + c0 * 1024);                 \
        gl_lds16(gB1 + ko_, (char*)Bs[buf] + c1 * 1024); } while (0)

    STAGE(0, 0);
    __builtin_amdgcn_sched_barrier(0);

    for (int kt = 0; kt < 4; ++kt) {
        int cur = kt & 1;
        if (kt < 3) {
            STAGE(kt + 1, cur ^ 1);
            __builtin_amdgcn_sched_barrier(0);
            asm volatile("s_waitcnt vmcnt(4)" ::: "memory");   // tile kt landed; kt+1 in flight
        } else {
            asm volatile("s_waitcnt vmcnt(0)" ::: "memory");
        }
        __builtin_amdgcn_sched_barrier(0);
        __builtin_amdgcn_s_barrier();
        __builtin_amdgcn_sched_barrier(0);
#pragma unroll
        for (int kh = 0; kh < 4; ++kh) {
            long long af[4], bf[4];
#pragma unroll
            for (int mi = 0; mi < 4; ++mi)
                af[mi] = *(const long long*)((const char*)As[cur] + pA[mi] + (((kh * 32) | g8) ^ sA[mi]));
#pragma unroll
            for (int ni = 0; ni < 4; ++ni)
                bf[ni] = *(const long long*)((const char*)Bs[cur] + pB[ni] + (((kh * 32) | g8) ^ sB[ni]));
#pragma unroll
            for (int mi = 0; mi < 4; ++mi)
#pragma unroll
                for (int ni = 0; ni < 4; ++ni)
                    acc[mi][ni] = __builtin_amdgcn_mfma_f32_16x16x32_fp8_fp8(
                        af[mi], bf[ni], acc[mi][ni], 0, 0, 0);
        }
        __builtin_amdgcn_sched_barrier(0);
        __builtin_amdgcn_s_barrier();
        __builtin_amdgcn_sched_barrier(0);
    }
#undef STAGE

    // epilogue: exp + per-token partial sums over this wave's 64 vocab cols
    float esum[4][4];   // [mi][r]
#pragma unroll
    for (int mi = 0; mi < 4; ++mi)
#pragma unroll
        for (int r = 0; r < 4; ++r) esum[mi][r] = 0.f;
#pragma unroll
    for (int ni = 0; ni < 4; ++ni) {
        int v = n0 + wc * 64 + ni * 16 + (lane & 15);
        bool ok = v < VOCAB;
        float bo = ok ? b_out[v] : 0.f;
#pragma unroll
        for (int mi = 0; mi < 4; ++mi)
#pragma unroll
            for (int r = 0; r < 4; ++r) {
                float logit = acc[mi][ni][r] + bo;
                esum[mi][r] += ok ? __expf(logit) : 0.f;
            }
    }
#pragma unroll
    for (int d = 1; d < 16; d <<= 1)
#pragma unroll
        for (int mi = 0; mi < 4; ++mi)
#pragma unroll
            for (int r = 0; r < 4; ++r) esum[mi][r] += __shfl_xor(esum[mi][r], d, 64);
    if ((lane & 15) == 0) {
#pragma unroll
        for (int mi = 0; mi < 4; ++mi)
#pragma unroll
            for (int r = 0; r < 4; ++r) {
                int tok = m0 + wr * 64 + mi * 16 + (lane >> 4) * 4 + r;
                partial[(size_t)tok * 512 + nb * 4 + wc] = esum[mi][r];
            }
    }
}

// ---------------- fixed-order reduce of partials -> lse ----------------
__global__ void k_reduce_lse(const float* __restrict__ partial, float* __restrict__ lse) {
    int tok = blockIdx.x * 4 + (threadIdx.x >> 6);
    int lane = threadIdx.x & 63;
    float s = 0.f;
    for (int j = lane; j < NVC; j += 64) s += partial[(size_t)tok * 512 + j];
#pragma unroll
    for (int d = 1; d < 64; d <<= 1) s += __shfl_xor(s, d, 64);
    if (lane == 0) lse[tok] = logf(s);
}

// ---------------- target logit (fp8 data): one wave per token ----------------
__global__ void k_tlogit(const unsigned char* __restrict__ HS8,
                         const unsigned char* __restrict__ W8,
                         const float* __restrict__ b_out,
                         const int* __restrict__ target,
                         float* __restrict__ tlg) {
    int tok = blockIdx.x * 4 + (threadIdx.x >> 6);
    int lane = threadIdx.x & 63;
    int tg = target[tok];
    uint2 ha = *(const uint2*)(HS8 + (size_t)tok * DIM + lane * 8);
    uint2 wa = *(const uint2*)(W8 + (size_t)tg * DIM + lane * 8);
    float s = 0.f;
#pragma unroll
    for (int i = 0; i < 4; ++i)
        s += e4m32f((ha.x >> (8 * i)) & 0xFF) * e4m32f((wa.x >> (8 * i)) & 0xFF);
#pragma unroll
    for (int i = 0; i < 4; ++i)
        s += e4m32f((ha.y >> (8 * i)) & 0xFF) * e4m32f((wa.y >> (8 * i)) & 0xFF);
#pragma unroll
    for (int d = 1; d < 64; d <<= 1) s += __shfl_xor(s, d, 64);
    if (lane == 0) tlg[tok] = s + b_out[tg];
}

// ---------------- loss + masked mean ----------------
__global__ void k_finalize(const float* __restrict__ lse, const float* __restrict__ tlg,
                           const int* __restrict__ target, float* __restrict__ out) {
    __shared__ float ssum[256];
    __shared__ float scnt[256];
    int t = threadIdx.x;
    float ls = 0.f, lc = 0.f;
    for (int i = t; i < TOKENS; i += 256) {
        int tg = target[i];
        float loss = (tg != 0) ? (lse[i] - tlg[i]) : 0.f;
        out[i] = loss;
        ls += loss;
        lc += (tg != 0) ? 1.f : 0.f;
    }
    ssum[t] = ls; scnt[t] = lc;
    __syncthreads();
    for (int d = 128; d > 0; d >>= 1) {
        if (t < d) { ssum[t] += ssum[t + d]; scnt[t] += scnt[t + d]; }
        __syncthreads();
    }
    if (t == 0) out[TOKENS] = ssum[0] / fmaxf(scnt[0], 1.f);
}

extern "C" void kernel_launch(void* const* d_in, const int* in_sizes, int n_in,
                              void* d_out, int out_size, void* d_ws, size_t ws_size,
                              hipStream_t stream) {
    const int*   review_input  = (const int*)d_in[2];
    const int*   review_target = (const int*)d_in[3];
    const float* word_emb      = (const float*)d_in[4];
    const float* W_ih          = (const float*)d_in[5];
    const float* W_hh          = (const float*)d_in[6];
    const float* b_ih          = (const float*)d_in[7];
    const float* b_hh          = (const float*)d_in[8];
    const float* W_out         = (const float*)d_in[9];
    const float* b_out         = (const float*)d_in[10];
    float* out = (float*)d_out;

    char* ws = (char*)d_ws;
    size_t off = 0;
    auto alloc = [&](size_t n) { char* p = ws + off; off += (n + 255) & ~(size_t)255; return p; };
    unsigned short* Xb    = (unsigned short*)alloc((size_t)TOKENS * DIM * 2);
    unsigned short* Wihb  = (unsigned short*)alloc((size_t)G3 * DIM * 2);
    unsigned short* Whhb  = (unsigned short*)alloc((size_t)G3 * HID * 2);
    unsigned char*  Wout8 = (unsigned char*)alloc((size_t)VOCAB * DIM);
    unsigned short* HS    = (unsigned short*)alloc((size_t)TOKENS * HID * 2);
    unsigned char*  HS8   = (unsigned char*)alloc((size_t)TOKENS * HID);
    unsigned short* hzero = (unsigned short*)alloc((size_t)BATCH * HID * 2);
    float* hf      = (float*)alloc((size_t)BATCH * HID * 4);
    float* GI      = (float*)alloc((size_t)TOKENS * G3 * 4);
    float* partial = (float*)alloc((size_t)TOKENS * 512 * 4);
    float* lse     = (float*)alloc((size_t)TOKENS * 4);
    float* tlg     = (float*)alloc((size_t)TOKENS * 4);
    (void)ws_size; (void)in_sizes; (void)n_in; (void)out_size;

    // weight conversions + embedding gather
    k_cvt_bf16<<<dim3((G3 * DIM / 8 + 255) / 256), dim3(256), 0, stream>>>(W_ih, Wihb, G3 * DIM / 8);
    k_cvt_bf16<<<dim3((G3 * HID / 8 + 255) / 256), dim3(256), 0, stream>>>(W_hh, Whhb, G3 * HID / 8);
    k_cvt_fp8<<<dim3((VOCAB * DIM / 16 + 255) / 256), dim3(256), 0, stream>>>(W_out, Wout8, VOCAB * DIM / 16);
    k_gather_x<<<dim3(TOKENS * DIM / 8 / 256), dim3(256), 0, stream>>>(word_emb, review_input, Xb);

    // GI = X @ W_ih^T + b_ih
    k_gemm_gi<<<dim3(TOKENS / 64, G3 / 64), dim3(256), 0, stream>>>(Xb, Wihb, b_ih, GI);

    // GRU recurrence: 50 per-step kernels, 256 blocks x 64 thr (all CUs);
    // fp8 h written inline (no separate conversion pass)
    hipMemsetAsync(hf, 0, (size_t)BATCH * HID * 4, stream);
    hipMemsetAsync(hzero, 0, (size_t)BATCH * HID * 2, stream);
    for (int s = 0; s < S_LEN; ++s) {
        const unsigned short* hin = s ? (HS + (size_t)(s - 1) * BATCH * HID) : hzero;
        unsigned short* hout = HS + (size_t)s * BATCH * HID;
        unsigned char*  hout8 = HS8 + (size_t)s * BATCH * HID;
        k_gru_step<<<dim3(256), dim3(64), 0, stream>>>(GI, Whhb, b_hh, hf, hin, hout, hout8, s);
    }

    // decode: partial exp-sums, reduce to lse, target logits, final loss
    k_decode<<<dim3(NWG), dim3(1024), 0, stream>>>(HS8, Wout8, b_out, partial);
    k_reduce_lse<<<dim3(TOKENS / 4), dim3(256), 0, stream>>>(partial, lse);
    k_tlogit<<<dim3(TOKENS / 4), dim3(256), 0, stream>>>(HS8, Wout8, b_out, review_target, tlg);
    k_finalize<<<dim3(1), dim3(256), 0, stream>>>(lse, tlg, review_target, out);
}

// Round 25
// 492.971 us; speedup vs baseline: 2.4623x; 1.0259x over previous
//
#include <hip/hip_runtime.h>
#include <hip/hip_bf16.h>

typedef __attribute__((ext_vector_type(8))) short short8;
typedef __attribute__((ext_vector_type(4))) float floatx4;

#define S_LEN  50
#define BATCH  128
#define DIM    512
#define HID    512
#define G3     1536
#define VOCAB  30000
#define TOKENS 6400
#define NB256  118      // ceil(30000/256) vocab chunks in decode
#define NVC    472      // partial columns = NB256 * 4 waves
#define NWG    (25 * NB256)   // 2950 decode blocks

__device__ __forceinline__ float bf2f(short u) {
    union { unsigned int i; float f; } c;
    c.i = ((unsigned int)(unsigned short)u) << 16;
    return c.f;
}
__device__ __forceinline__ unsigned short f2bf(float x) {
    __hip_bfloat16 h = __float2bfloat16(x);
    unsigned short u;
    __builtin_memcpy(&u, &h, 2);
    return u;
}
// f32 -> OCP e4m3fn, RNE, branchless (selects only). Clamps to +-448, no NaN byte.
__device__ __forceinline__ unsigned char f2e4m3(float x) {
    union { float f; unsigned u; } v; v.f = x;
    unsigned s = (v.u >> 24) & 0x80u;
    v.u &= 0x7FFFFFFFu;
    float af = fminf(v.f, 448.f);              // clamp (also kills inf)
    // normal-path encode (valid when af >= 2^-6)
    union { float f; unsigned u; } w; w.f = af;
    unsigned lsb = (w.u >> 20) & 1u;
    unsigned wr  = w.u + 0x7FFFFu + lsb;       // RNE at bit 20
    unsigned nrm = (((wr >> 23) & 0xFFu) - 120u) * 8u + ((wr >> 20) & 7u);
    // subnormal-path encode (units of 2^-9, RNE via rintf)
    unsigned sub = (unsigned)(int)rintf(af * 512.f);
    unsigned mag = (af < 0.015625f) ? sub : nrm;
    return (unsigned char)(s | mag);
}
__device__ __forceinline__ float e4m32f(unsigned b) {
    unsigned s = b & 0x80u, e = (b >> 3) & 0xFu, m = b & 7u;
    float fs = (float)m * 0.001953125f;
    union { unsigned u; float f; } v;
    v.u = ((e + 120u) << 23) | (m << 20);
    float mag = (e == 0) ? fs : v.f;
    return s ? -mag : mag;
}

// ---------------- f32 -> bf16 bulk convert (8 elems/thread) ----------------
__global__ void k_cvt_bf16(const float* __restrict__ src,
                           unsigned short* __restrict__ dst, int n8) {
    int g = blockIdx.x * 256 + threadIdx.x;
    if (g >= n8) return;
    const float* s = src + (size_t)g * 8;
    union { short8 v; unsigned short u[8]; } o;
#pragma unroll
    for (int i = 0; i < 8; ++i) o.u[i] = f2bf(s[i]);
    *(short8*)(dst + (size_t)g * 8) = o.v;
}

// ---------------- f32 -> fp8 e4m3 bulk convert (16 elems/thread) ----------------
__global__ void k_cvt_fp8(const float* __restrict__ src,
                          unsigned char* __restrict__ dst, int n16) {
    int g = blockIdx.x * 256 + threadIdx.x;
    if (g >= n16) return;
    const float* s = src + (size_t)g * 16;
    union { uint4 v; unsigned char b[16]; } o;
#pragma unroll
    for (int i = 0; i < 16; ++i) o.b[i] = f2e4m3(s[i]);
    *(uint4*)(dst + (size_t)g * 16) = o.v;
}

// ---------------- embedding gather + convert: X[token][512] bf16 ----------------
__global__ void k_gather_x(const float* __restrict__ emb, const int* __restrict__ idx,
                           unsigned short* __restrict__ X) {
    int g = blockIdx.x * 256 + threadIdx.x;   // 8-elem group; total TOKENS*DIM/8
    int token = g >> 6;                       // 64 groups per token
    int chunk = (g & 63) << 3;
    const float* src = emb + (size_t)idx[token] * DIM + chunk;
    union { short8 v; unsigned short u[8]; } o;
#pragma unroll
    for (int i = 0; i < 8; ++i) o.u[i] = f2bf(src[i]);
    *(short8*)(X + (size_t)token * DIM + chunk) = o.v;
}

// ---------------- GI = X @ W_ih^T + b_ih   [6400 x 1536] fp32 ----------------
__launch_bounds__(256)
__global__ void k_gemm_gi(const unsigned short* __restrict__ X,
                          const unsigned short* __restrict__ Wih,
                          const float* __restrict__ b_ih,
                          float* __restrict__ GI) {
    __shared__ unsigned short As[64][72];
    __shared__ unsigned short Bs[64][72];
    int m0 = blockIdx.x * 64;
    int n0 = blockIdx.y * 64;
    int t = threadIdx.x;
    int w = t >> 6, lane = t & 63;
    floatx4 zero = {0.f, 0.f, 0.f, 0.f};
    floatx4 acc[4];
#pragma unroll
    for (int i = 0; i < 4; ++i) acc[i] = zero;
    int srow = t >> 2, scol = (t & 3) * 16;
    for (int k0 = 0; k0 < DIM; k0 += 64) {
        *(short8*)&As[srow][scol]     = *(const short8*)(X   + (size_t)(m0 + srow) * DIM + k0 + scol);
        *(short8*)&As[srow][scol + 8] = *(const short8*)(X   + (size_t)(m0 + srow) * DIM + k0 + scol + 8);
        *(short8*)&Bs[srow][scol]     = *(const short8*)(Wih + (size_t)(n0 + srow) * DIM + k0 + scol);
        *(short8*)&Bs[srow][scol + 8] = *(const short8*)(Wih + (size_t)(n0 + srow) * DIM + k0 + scol + 8);
        __syncthreads();
#pragma unroll
        for (int kt = 0; kt < 2; ++kt) {
            short8 a = *(const short8*)&As[w * 16 + (lane & 15)][kt * 32 + (lane >> 4) * 8];
#pragma unroll
            for (int nt = 0; nt < 4; ++nt) {
                short8 b = *(const short8*)&Bs[nt * 16 + (lane & 15)][kt * 32 + (lane >> 4) * 8];
                acc[nt] = __builtin_amdgcn_mfma_f32_16x16x32_bf16(a, b, acc[nt], 0, 0, 0);
            }
        }
        __syncthreads();
    }
#pragma unroll
    for (int nt = 0; nt < 4; ++nt)
#pragma unroll
        for (int r = 0; r < 4; ++r) {
            int row = m0 + w * 16 + (lane >> 4) * 4 + r;
            int col = n0 + nt * 16 + (lane & 15);
            GI[(size_t)row * G3 + col] = acc[nt][r] + b_ih[col];
        }
}

// ---------------- GRU single step: 256 blocks x 64 thr (all CUs) ----------------
// Writes both bf16 h (for next step's MFMA A-operand) and fp8 h (for decode).
__launch_bounds__(64)
__global__ void k_gru_step(const float* __restrict__ GI,
                           const unsigned short* __restrict__ Whh,
                           const float* __restrict__ b_hh,
                           float* __restrict__ hf,
                           const unsigned short* __restrict__ hin,
                           unsigned short* __restrict__ hout,
                           unsigned char* __restrict__ hout8,
                           int s) {
    int lane = threadIdx.x & 63;
    int bg = blockIdx.x & 7;      // batch group (8 groups of 16)
    int hs = blockIdx.x >> 3;     // hidden slice (32 slices of 16)
    int jc = hs * 16 + (lane & 15);   // hidden unit (N index)

    const unsigned short* pa  = hin + (size_t)(bg * 16 + (lane & 15)) * HID + (lane >> 4) * 8;
    const unsigned short* pb0 = Whh + (size_t)(0 * HID + jc) * DIM + (lane >> 4) * 8;
    const unsigned short* pb1 = Whh + (size_t)(1 * HID + jc) * DIM + (lane >> 4) * 8;
    const unsigned short* pb2 = Whh + (size_t)(2 * HID + jc) * DIM + (lane >> 4) * 8;

    floatx4 acc0 = {0.f, 0.f, 0.f, 0.f};
    floatx4 acc1 = {0.f, 0.f, 0.f, 0.f};
    floatx4 acc2 = {0.f, 0.f, 0.f, 0.f};
#pragma unroll
    for (int kt = 0; kt < 16; ++kt) {
        short8 a = *(const short8*)(pa + kt * 32);
        acc0 = __builtin_amdgcn_mfma_f32_16x16x32_bf16(a, *(const short8*)(pb0 + kt * 32), acc0, 0, 0, 0);
        acc1 = __builtin_amdgcn_mfma_f32_16x16x32_bf16(a, *(const short8*)(pb1 + kt * 32), acc1, 0, 0, 0);
        acc2 = __builtin_amdgcn_mfma_f32_16x16x32_bf16(a, *(const short8*)(pb2 + kt * 32), acc2, 0, 0, 0);
    }
    float bhr = b_hh[jc], bhz = b_hh[jc + 512], bhn = b_hh[jc + 1024];
#pragma unroll
    for (int r = 0; r < 4; ++r) {
        int brow = bg * 16 + (lane >> 4) * 4 + r;   // batch row (M index)
        int tok = s * BATCH + brow;
        const float* gi = GI + (size_t)tok * G3;
        float rg = 1.f / (1.f + __expf(-(gi[jc] + acc0[r] + bhr)));
        float zg = 1.f / (1.f + __expf(-(gi[jc + 512] + acc1[r] + bhz)));
        float ng = tanhf(gi[jc + 1024] + rg * (acc2[r] + bhn));
        size_t hidx = (size_t)brow * HID + jc;
        float hn = (1.f - zg) * ng + zg * hf[hidx];
        hf[hidx] = hn;
        float hb = bf2f((short)f2bf(hn));          // decode sees fp8(bf16(h))
        hout[hidx] = f2bf(hn);
        hout8[hidx] = f2e4m3(hb);
    }
}

// ---------------- decode: fp8 MFMA, 256x256 tile, reg-staged 8B-swizzled LDS ----------------
// 16 waves (4x4), 64x64/wave, fp8 K-tiles of 128 (4 iters), mfma_f32_16x16x32_fp8_fp8.
// LDS layout: byte d of row r holds global byte (d&127) ^ ((r&15)<<3) — 8-byte
// granularity keys make BOTH ds_write_b64 and ds_read_b64 conflict-free (each
// bank-pair hit exactly 4x per wave instr = structural minimum).
// Schedule: R11-proven reg-staged dbuf (load-early / write-late, 1 barrier/iter).
__launch_bounds__(1024, 4)
__global__ void k_decode(const unsigned char* __restrict__ HS8,
                         const unsigned char* __restrict__ W8,
                         const float* __restrict__ b_out,
                         float* __restrict__ partial) {
    __shared__ unsigned char As[2][32768];
    __shared__ unsigned char Bs[2][32768];

    // bijective XCD chunk swizzle (nwg=2950, q=368, r=6)
    int bid = blockIdx.x;
    int xcd = bid & 7, pos = bid >> 3;
    int p = (xcd < 6 ? xcd * 369 : 2214 + (xcd - 6) * 368) + pos;
    // supergroup order: 14 groups of 8 nb + 1 group of 6 nb; mb-major within group
    int sgrp = p / 200;
    int rr   = p - sgrp * 200;
    int mb, nb;
    if (sgrp < 14) { mb = rr >> 3; nb = sgrp * 8 + (rr & 7); }
    else           { int q6 = rr / 6; mb = q6; nb = 112 + (rr - q6 * 6); }
    int m0 = mb * 256, n0 = nb * 256;

    int t = threadIdx.x, w = t >> 6, lane = t & 63;
    int wr = w >> 2, wc = w & 3;            // 4x4 wave grid

    floatx4 zero = {0.f, 0.f, 0.f, 0.f};
    floatx4 acc[4][4];
#pragma unroll
    for (int mi = 0; mi < 4; ++mi)
#pragma unroll
        for (int ni = 0; ni < 4; ++ni) acc[mi][ni] = zero;

    // staging: thread t stages 32 B of A-row (t>>2) and of B-row per K-tile.
    int sr = t >> 2;                        // tile row 0..255
    int sc = (t & 3) * 32;                  // byte col 0/32/64/96
    int wS = (sr & 15) << 3;                // 8-B-granularity swizzle key
    const unsigned char* gA = HS8 + (size_t)(m0 + sr) * DIM + sc;
    int vr = n0 + sr; if (vr > VOCAB - 1) vr = VOCAB - 1;
    const unsigned char* gB = W8 + (size_t)vr * DIM + sc;
    int wb = sr * 128;
    int w0 = wb + ((sc +  0) ^ wS);
    int w1 = wb + ((sc +  8) ^ wS);
    int w2 = wb + ((sc + 16) ^ wS);
    int w3 = wb + ((sc + 24) ^ wS);

    // read fragment row bases; key is shared (row&15 == lane&15 for all frags)
    int g8 = (lane >> 4) * 8;
    int sK = (lane & 15) << 3;
    int pA[4], pB[4];
#pragma unroll
    for (int mi = 0; mi < 4; ++mi) pA[mi] = (wr * 64 + mi * 16 + (lane & 15)) * 128;
#pragma unroll
    for (int ni = 0; ni < 4; ++ni) pB[ni] = (wc * 64 + ni * 16 + (lane & 15)) * 128;

    union Q { uint4 v; long long q[2]; };
    Q a0, a1, b0, b1;
    a0.v = *(const uint4*)(gA);      a1.v = *(const uint4*)(gA + 16);
    b0.v = *(const uint4*)(gB);      b1.v = *(const uint4*)(gB + 16);
#define WRT(buf) do {                                              \
        *(long long*)((char*)As[buf] + w0) = a0.q[0];              \
        *(long long*)((char*)As[buf] + w1) = a0.q[1];              \
        *(long long*)((char*)As[buf] + w2) = a1.q[0];              \
        *(long long*)((char*)As[buf] + w3) = a1.q[1];              \
        *(long long*)((char*)Bs[buf] + w0) = b0.q[0];              \
        *(long long*)((char*)Bs[buf] + w1) = b0.q[1];              \
        *(long long*)((char*)Bs[buf] + w2) = b1.q[0];              \
        *(long long*)((char*)Bs[buf] + w3) = b1.q[1];              \
    } while (0)
    WRT(0);
    __syncthreads();

    for (int kt = 0; kt < 4; ++kt) {
        int cur = kt & 1;
        if (kt < 3) {                        // issue next-tile loads early (T14)
            int ko = (kt + 1) * 128;
            a0.v = *(const uint4*)(gA + ko);  a1.v = *(const uint4*)(gA + ko + 16);
            b0.v = *(const uint4*)(gB + ko);  b1.v = *(const uint4*)(gB + ko + 16);
        }
#pragma unroll
        for (int kh = 0; kh < 4; ++kh) {
            int ck = ((kh * 32) | g8) ^ sK;
            long long af[4], bf[4];
#pragma unroll
            for (int mi = 0; mi < 4; ++mi)
                af[mi] = *(const long long*)((const char*)As[cur] + pA[mi] + ck);
#pragma unroll
            for (int ni = 0; ni < 4; ++ni)
                bf[ni] = *(const long long*)((const char*)Bs[cur] + pB[ni] + ck);
#pragma unroll
            for (int mi = 0; mi < 4; ++mi)
#pragma unroll
                for (int ni = 0; ni < 4; ++ni)
                    acc[mi][ni] = __builtin_amdgcn_mfma_f32_16x16x32_fp8_fp8(
                        af[mi], bf[ni], acc[mi][ni], 0, 0, 0);
        }
        if (kt < 3) WRT(cur ^ 1);            // write staged tile to other buffer
        __syncthreads();                     // single barrier per K-iter (R11-proven)
    }
#undef WRT

    // epilogue: exp + per-token partial sums over this wave's 64 vocab cols
    float esum[4][4];   // [mi][r]
#pragma unroll
    for (int mi = 0; mi < 4; ++mi)
#pragma unroll
        for (int r = 0; r < 4; ++r) esum[mi][r] = 0.f;
#pragma unroll
    for (int ni = 0; ni < 4; ++ni) {
        int v = n0 + wc * 64 + ni * 16 + (lane & 15);
        bool ok = v < VOCAB;
        float bo = ok ? b_out[v] : 0.f;
#pragma unroll
        for (int mi = 0; mi < 4; ++mi)
#pragma unroll
            for (int r = 0; r < 4; ++r) {
                float logit = acc[mi][ni][r] + bo;
                esum[mi][r] += ok ? __expf(logit) : 0.f;
            }
    }
#pragma unroll
    for (int d = 1; d < 16; d <<= 1)
#pragma unroll
        for (int mi = 0; mi < 4; ++mi)
#pragma unroll
            for (int r = 0; r < 4; ++r) esum[mi][r] += __shfl_xor(esum[mi][r], d, 64);
    if ((lane & 15) == 0) {
#pragma unroll
        for (int mi = 0; mi < 4; ++mi)
#pragma unroll
            for (int r = 0; r < 4; ++r) {
                int tok = m0 + wr * 64 + mi * 16 + (lane >> 4) * 4 + r;
                partial[(size_t)tok * 512 + nb * 4 + wc] = esum[mi][r];
            }
    }
}

// ---------------- fixed-order reduce of partials -> lse ----------------
__global__ void k_reduce_lse(const float* __restrict__ partial, float* __restrict__ lse) {
    int tok = blockIdx.x * 4 + (threadIdx.x >> 6);
    int lane = threadIdx.x & 63;
    float s = 0.f;
    for (int j = lane; j < NVC; j += 64) s += partial[(size_t)tok * 512 + j];
#pragma unroll
    for (int d = 1; d < 64; d <<= 1) s += __shfl_xor(s, d, 64);
    if (lane == 0) lse[tok] = logf(s);
}

// ---------------- target logit (fp8 data): one wave per token ----------------
__global__ void k_tlogit(const unsigned char* __restrict__ HS8,
                         const unsigned char* __restrict__ W8,
                         const float* __restrict__ b_out,
                         const int* __restrict__ target,
                         float* __restrict__ tlg) {
    int tok = blockIdx.x * 4 + (threadIdx.x >> 6);
    int lane = threadIdx.x & 63;
    int tg = target[tok];
    uint2 ha = *(const uint2*)(HS8 + (size_t)tok * DIM + lane * 8);
    uint2 wa = *(const uint2*)(W8 + (size_t)tg * DIM + lane * 8);
    float s = 0.f;
#pragma unroll
    for (int i = 0; i < 4; ++i)
        s += e4m32f((ha.x >> (8 * i)) & 0xFF) * e4m32f((wa.x >> (8 * i)) & 0xFF);
#pragma unroll
    for (int i = 0; i < 4; ++i)
        s += e4m32f((ha.y >> (8 * i)) & 0xFF) * e4m32f((wa.y >> (8 * i)) & 0xFF);
#pragma unroll
    for (int d = 1; d < 64; d <<= 1) s += __shfl_xor(s, d, 64);
    if (lane == 0) tlg[tok] = s + b_out[tg];
}

// ---------------- loss + masked mean ----------------
__global__ void k_finalize(const float* __restrict__ lse, const float* __restrict__ tlg,
                           const int* __restrict__ target, float* __restrict__ out) {
    __shared__ float ssum[256];
    __shared__ float scnt[256];
    int t = threadIdx.x;
    float ls = 0.f, lc = 0.f;
    for (int i = t; i < TOKENS; i += 256) {
        int tg = target[i];
        float loss = (tg != 0) ? (lse[i] - tlg[i]) : 0.f;
        out[i] = loss;
        ls += loss;
        lc += (tg != 0) ? 1.f : 0.f;
    }
    ssum[t] = ls; scnt[t] = lc;
    __syncthreads();
    for (int d = 128; d > 0; d >>= 1) {
        if (t < d) { ssum[t] += ssum[t + d]; scnt[t] += scnt[t + d]; }
        __syncthreads();
    }
    if (t == 0) out[TOKENS] = ssum[0] / fmaxf(scnt[0], 1.f);
}

extern "C" void kernel_launch(void* const* d_in, const int* in_sizes, int n_in,
                              void* d_out, int out_size, void* d_ws, size_t ws_size,
                              hipStream_t stream) {
    const int*   review_input  = (const int*)d_in[2];
    const int*   review_target = (const int*)d_in[3];
    const float* word_emb      = (const float*)d_in[4];
    const float* W_ih          = (const float*)d_in[5];
    const float* W_hh          = (const float*)d_in[6];
    const float* b_ih          = (const float*)d_in[7];
    const float* b_hh          = (const float*)d_in[8];
    const float* W_out         = (const float*)d_in[9];
    const float* b_out         = (const float*)d_in[10];
    float* out = (float*)d_out;

    char* ws = (char*)d_ws;
    size_t off = 0;
    auto alloc = [&](size_t n) { char* p = ws + off; off += (n + 255) & ~(size_t)255; return p; };
    unsigned short* Xb    = (unsigned short*)alloc((size_t)TOKENS * DIM * 2);
    unsigned short* Wihb  = (unsigned short*)alloc((size_t)G3 * DIM * 2);
    unsigned short* Whhb  = (unsigned short*)alloc((size_t)G3 * HID * 2);
    unsigned char*  Wout8 = (unsigned char*)alloc((size_t)VOCAB * DIM);
    unsigned short* HS    = (unsigned short*)alloc((size_t)TOKENS * HID * 2);
    unsigned char*  HS8   = (unsigned char*)alloc((size_t)TOKENS * HID);
    unsigned short* hzero = (unsigned short*)alloc((size_t)BATCH * HID * 2);
    float* hf      = (float*)alloc((size_t)BATCH * HID * 4);
    float* GI      = (float*)alloc((size_t)TOKENS * G3 * 4);
    float* partial = (float*)alloc((size_t)TOKENS * 512 * 4);
    float* lse     = (float*)alloc((size_t)TOKENS * 4);
    float* tlg     = (float*)alloc((size_t)TOKENS * 4);
    (void)ws_size; (void)in_sizes; (void)n_in; (void)out_size;

    // weight conversions + embedding gather
    k_cvt_bf16<<<dim3((G3 * DIM / 8 + 255) / 256), dim3(256), 0, stream>>>(W_ih, Wihb, G3 * DIM / 8);
    k_cvt_bf16<<<dim3((G3 * HID / 8 + 255) / 256), dim3(256), 0, stream>>>(W_hh, Whhb, G3 * HID / 8);
    k_cvt_fp8<<<dim3((VOCAB * DIM / 16 + 255) / 256), dim3(256), 0, stream>>>(W_out, Wout8, VOCAB * DIM / 16);
    k_gather_x<<<dim3(TOKENS * DIM / 8 / 256), dim3(256), 0, stream>>>(word_emb, review_input, Xb);

    // GI = X @ W_ih^T + b_ih
    k_gemm_gi<<<dim3(TOKENS / 64, G3 / 64), dim3(256), 0, stream>>>(Xb, Wihb, b_ih, GI);

    // GRU recurrence: 50 per-step kernels, 256 blocks x 64 thr (all CUs);
    // fp8 h written inline (no separate conversion pass)
    hipMemsetAsync(hf, 0, (size_t)BATCH * HID * 4, stream);
    hipMemsetAsync(hzero, 0, (size_t)BATCH * HID * 2, stream);
    for (int s = 0; s < S_LEN; ++s) {
        const unsigned short* hin = s ? (HS + (size_t)(s - 1) * BATCH * HID) : hzero;
        unsigned short* hout = HS + (size_t)s * BATCH * HID;
        unsigned char*  hout8 = HS8 + (size_t)s * BATCH * HID;
        k_gru_step<<<dim3(256), dim3(64), 0, stream>>>(GI, Whhb, b_hh, hf, hin, hout, hout8, s);
    }

    // decode: partial exp-sums, reduce to lse, target logits, final loss
    k_decode<<<dim3(NWG), dim3(1024), 0, stream>>>(HS8, Wout8, b_out, partial);
    k_reduce_lse<<<dim3(TOKENS / 4), dim3(256), 0, stream>>>(partial, lse);
    k_tlogit<<<dim3(TOKENS / 4), dim3(256), 0, stream>>>(HS8, Wout8, b_out, review_target, tlg);
    k_finalize<<<dim3(1), dim3(256), 0, stream>>>(lse, tlg, review_target, out);
}

// Round 26
// 491.630 us; speedup vs baseline: 2.4690x; 1.0027x over previous
//
#include <hip/hip_runtime.h>
#include <hip/hip_bf16.h>

typedef __attribute__((ext_vector_type(8))) short short8;
typedef __attribute__((ext_vector_type(4))) float floatx4;

#define S_LEN  50
#define BATCH  128
#define DIM    512
#define HID    512
#define G3     1536
#define VOCAB  30000
#define TOKENS 6400
#define NB256  118      // ceil(30000/256) vocab chunks in decode
#define NVC    472      // partial columns = NB256 * 4 waves
#define NWG    (25 * NB256)   // 2950 decode blocks

__device__ __forceinline__ float bf2f(short u) {
    union { unsigned int i; float f; } c;
    c.i = ((unsigned int)(unsigned short)u) << 16;
    return c.f;
}
__device__ __forceinline__ unsigned short f2bf(float x) {
    __hip_bfloat16 h = __float2bfloat16(x);
    unsigned short u;
    __builtin_memcpy(&u, &h, 2);
    return u;
}
// f32 -> OCP e4m3fn, RNE, branchless (selects only). Clamps to +-448, no NaN byte.
__device__ __forceinline__ unsigned char f2e4m3(float x) {
    union { float f; unsigned u; } v; v.f = x;
    unsigned s = (v.u >> 24) & 0x80u;
    v.u &= 0x7FFFFFFFu;
    float af = fminf(v.f, 448.f);              // clamp (also kills inf)
    // normal-path encode (valid when af >= 2^-6)
    union { float f; unsigned u; } w; w.f = af;
    unsigned lsb = (w.u >> 20) & 1u;
    unsigned wr  = w.u + 0x7FFFFu + lsb;       // RNE at bit 20
    unsigned nrm = (((wr >> 23) & 0xFFu) - 120u) * 8u + ((wr >> 20) & 7u);
    // subnormal-path encode (units of 2^-9, RNE via rintf)
    unsigned sub = (unsigned)(int)rintf(af * 512.f);
    unsigned mag = (af < 0.015625f) ? sub : nrm;
    return (unsigned char)(s | mag);
}
__device__ __forceinline__ float e4m32f(unsigned b) {
    unsigned s = b & 0x80u, e = (b >> 3) & 0xFu, m = b & 7u;
    float fs = (float)m * 0.001953125f;
    union { unsigned u; float f; } v;
    v.u = ((e + 120u) << 23) | (m << 20);
    float mag = (e == 0) ? fs : v.f;
    return s ? -mag : mag;
}

// ---------------- f32 -> bf16 bulk convert (8 elems/thread) ----------------
__global__ void k_cvt_bf16(const float* __restrict__ src,
                           unsigned short* __restrict__ dst, int n8) {
    int g = blockIdx.x * 256 + threadIdx.x;
    if (g >= n8) return;
    const float* s = src + (size_t)g * 8;
    union { short8 v; unsigned short u[8]; } o;
#pragma unroll
    for (int i = 0; i < 8; ++i) o.u[i] = f2bf(s[i]);
    *(short8*)(dst + (size_t)g * 8) = o.v;
}

// ---------------- f32 -> fp8 e4m3 bulk convert (16 elems/thread) ----------------
__global__ void k_cvt_fp8(const float* __restrict__ src,
                          unsigned char* __restrict__ dst, int n16) {
    int g = blockIdx.x * 256 + threadIdx.x;
    if (g >= n16) return;
    const float* s = src + (size_t)g * 16;
    union { uint4 v; unsigned char b[16]; } o;
#pragma unroll
    for (int i = 0; i < 16; ++i) o.b[i] = f2e4m3(s[i]);
    *(uint4*)(dst + (size_t)g * 16) = o.v;
}

// ---------------- embedding gather + convert: X[token][512] bf16 ----------------
__global__ void k_gather_x(const float* __restrict__ emb, const int* __restrict__ idx,
                           unsigned short* __restrict__ X) {
    int g = blockIdx.x * 256 + threadIdx.x;   // 8-elem group; total TOKENS*DIM/8
    int token = g >> 6;                       // 64 groups per token
    int chunk = (g & 63) << 3;
    const float* src = emb + (size_t)idx[token] * DIM + chunk;
    union { short8 v; unsigned short u[8]; } o;
#pragma unroll
    for (int i = 0; i < 8; ++i) o.u[i] = f2bf(src[i]);
    *(short8*)(X + (size_t)token * DIM + chunk) = o.v;
}

// ---------------- GI = X @ W_ih^T + b_ih   [6400 x 1536] fp32 ----------------
__launch_bounds__(256)
__global__ void k_gemm_gi(const unsigned short* __restrict__ X,
                          const unsigned short* __restrict__ Wih,
                          const float* __restrict__ b_ih,
                          float* __restrict__ GI) {
    __shared__ unsigned short As[64][72];
    __shared__ unsigned short Bs[64][72];
    int m0 = blockIdx.x * 64;
    int n0 = blockIdx.y * 64;
    int t = threadIdx.x;
    int w = t >> 6, lane = t & 63;
    floatx4 zero = {0.f, 0.f, 0.f, 0.f};
    floatx4 acc[4];
#pragma unroll
    for (int i = 0; i < 4; ++i) acc[i] = zero;
    int srow = t >> 2, scol = (t & 3) * 16;
    for (int k0 = 0; k0 < DIM; k0 += 64) {
        *(short8*)&As[srow][scol]     = *(const short8*)(X   + (size_t)(m0 + srow) * DIM + k0 + scol);
        *(short8*)&As[srow][scol + 8] = *(const short8*)(X   + (size_t)(m0 + srow) * DIM + k0 + scol + 8);
        *(short8*)&Bs[srow][scol]     = *(const short8*)(Wih + (size_t)(n0 + srow) * DIM + k0 + scol);
        *(short8*)&Bs[srow][scol + 8] = *(const short8*)(Wih + (size_t)(n0 + srow) * DIM + k0 + scol + 8);
        __syncthreads();
#pragma unroll
        for (int kt = 0; kt < 2; ++kt) {
            short8 a = *(const short8*)&As[w * 16 + (lane & 15)][kt * 32 + (lane >> 4) * 8];
#pragma unroll
            for (int nt = 0; nt < 4; ++nt) {
                short8 b = *(const short8*)&Bs[nt * 16 + (lane & 15)][kt * 32 + (lane >> 4) * 8];
                acc[nt] = __builtin_amdgcn_mfma_f32_16x16x32_bf16(a, b, acc[nt], 0, 0, 0);
            }
        }
        __syncthreads();
    }
#pragma unroll
    for (int nt = 0; nt < 4; ++nt)
#pragma unroll
        for (int r = 0; r < 4; ++r) {
            int row = m0 + w * 16 + (lane >> 4) * 4 + r;
            int col = n0 + nt * 16 + (lane & 15);
            GI[(size_t)row * G3 + col] = acc[nt][r] + b_ih[col];
        }
}

// ---------------- GRU single step: 256 blocks x 64 thr (all CUs) ----------------
// Writes both bf16 h (for next step's MFMA A-operand) and fp8 h (for decode).
__launch_bounds__(64)
__global__ void k_gru_step(const float* __restrict__ GI,
                           const unsigned short* __restrict__ Whh,
                           const float* __restrict__ b_hh,
                           float* __restrict__ hf,
                           const unsigned short* __restrict__ hin,
                           unsigned short* __restrict__ hout,
                           unsigned char* __restrict__ hout8,
                           int s) {
    int lane = threadIdx.x & 63;
    int bg = blockIdx.x & 7;      // batch group (8 groups of 16)
    int hs = blockIdx.x >> 3;     // hidden slice (32 slices of 16)
    int jc = hs * 16 + (lane & 15);   // hidden unit (N index)

    const unsigned short* pa  = hin + (size_t)(bg * 16 + (lane & 15)) * HID + (lane >> 4) * 8;
    const unsigned short* pb0 = Whh + (size_t)(0 * HID + jc) * DIM + (lane >> 4) * 8;
    const unsigned short* pb1 = Whh + (size_t)(1 * HID + jc) * DIM + (lane >> 4) * 8;
    const unsigned short* pb2 = Whh + (size_t)(2 * HID + jc) * DIM + (lane >> 4) * 8;

    floatx4 acc0 = {0.f, 0.f, 0.f, 0.f};
    floatx4 acc1 = {0.f, 0.f, 0.f, 0.f};
    floatx4 acc2 = {0.f, 0.f, 0.f, 0.f};
#pragma unroll
    for (int kt = 0; kt < 16; ++kt) {
        short8 a = *(const short8*)(pa + kt * 32);
        acc0 = __builtin_amdgcn_mfma_f32_16x16x32_bf16(a, *(const short8*)(pb0 + kt * 32), acc0, 0, 0, 0);
        acc1 = __builtin_amdgcn_mfma_f32_16x16x32_bf16(a, *(const short8*)(pb1 + kt * 32), acc1, 0, 0, 0);
        acc2 = __builtin_amdgcn_mfma_f32_16x16x32_bf16(a, *(const short8*)(pb2 + kt * 32), acc2, 0, 0, 0);
    }
    float bhr = b_hh[jc], bhz = b_hh[jc + 512], bhn = b_hh[jc + 1024];
#pragma unroll
    for (int r = 0; r < 4; ++r) {
        int brow = bg * 16 + (lane >> 4) * 4 + r;   // batch row (M index)
        int tok = s * BATCH + brow;
        const float* gi = GI + (size_t)tok * G3;
        float rg = 1.f / (1.f + __expf(-(gi[jc] + acc0[r] + bhr)));
        float zg = 1.f / (1.f + __expf(-(gi[jc + 512] + acc1[r] + bhz)));
        float ng = tanhf(gi[jc + 1024] + rg * (acc2[r] + bhn));
        size_t hidx = (size_t)brow * HID + jc;
        float hn = (1.f - zg) * ng + zg * hf[hidx];
        hf[hidx] = hn;
        float hb = bf2f((short)f2bf(hn));          // decode sees fp8(bf16(h))
        hout[hidx] = f2bf(hn);
        hout8[hidx] = f2e4m3(hb);
    }
}

// ---------------- decode: fp8 MFMA, 256x256 tile, reg-staged 8B-swizzled LDS ----------------
// R25-proven: 16 waves (4x4), 64x64/wave, fp8 K-tiles of 128 (4 iters),
// mfma_f32_16x16x32_fp8_fp8; conflict-free 8-B-granularity XOR swizzle on both
// ds_write_b64 and ds_read_b64; reg-staged dbuf (load-early / write-late).
__launch_bounds__(1024, 4)
__global__ void k_decode(const unsigned char* __restrict__ HS8,
                         const unsigned char* __restrict__ W8,
                         const float* __restrict__ b_out,
                         float* __restrict__ partial) {
    __shared__ unsigned char As[2][32768];
    __shared__ unsigned char Bs[2][32768];

    // bijective XCD chunk swizzle (nwg=2950, q=368, r=6)
    int bid = blockIdx.x;
    int xcd = bid & 7, pos = bid >> 3;
    int p = (xcd < 6 ? xcd * 369 : 2214 + (xcd - 6) * 368) + pos;
    // supergroup order: 14 groups of 8 nb + 1 group of 6 nb; mb-major within group
    int sgrp = p / 200;
    int rr   = p - sgrp * 200;
    int mb, nb;
    if (sgrp < 14) { mb = rr >> 3; nb = sgrp * 8 + (rr & 7); }
    else           { int q6 = rr / 6; mb = q6; nb = 112 + (rr - q6 * 6); }
    int m0 = mb * 256, n0 = nb * 256;

    int t = threadIdx.x, w = t >> 6, lane = t & 63;
    int wr = w >> 2, wc = w & 3;            // 4x4 wave grid

    floatx4 zero = {0.f, 0.f, 0.f, 0.f};
    floatx4 acc[4][4];
#pragma unroll
    for (int mi = 0; mi < 4; ++mi)
#pragma unroll
        for (int ni = 0; ni < 4; ++ni) acc[mi][ni] = zero;

    // staging: thread t stages 32 B of A-row (t>>2) and of B-row per K-tile.
    int sr = t >> 2;                        // tile row 0..255
    int sc = (t & 3) * 32;                  // byte col 0/32/64/96
    int wS = (sr & 15) << 3;                // 8-B-granularity swizzle key
    const unsigned char* gA = HS8 + (size_t)(m0 + sr) * DIM + sc;
    int vr = n0 + sr; if (vr > VOCAB - 1) vr = VOCAB - 1;
    const unsigned char* gB = W8 + (size_t)vr * DIM + sc;
    int wb = sr * 128;
    int w0 = wb + ((sc +  0) ^ wS);
    int w1 = wb + ((sc +  8) ^ wS);
    int w2 = wb + ((sc + 16) ^ wS);
    int w3 = wb + ((sc + 24) ^ wS);

    // read fragment row bases; key is shared (row&15 == lane&15 for all frags)
    int g8 = (lane >> 4) * 8;
    int sK = (lane & 15) << 3;
    int pA[4], pB[4];
#pragma unroll
    for (int mi = 0; mi < 4; ++mi) pA[mi] = (wr * 64 + mi * 16 + (lane & 15)) * 128;
#pragma unroll
    for (int ni = 0; ni < 4; ++ni) pB[ni] = (wc * 64 + ni * 16 + (lane & 15)) * 128;

    union Q { uint4 v; long long q[2]; };
    Q a0, a1, b0, b1;
    a0.v = *(const uint4*)(gA);      a1.v = *(const uint4*)(gA + 16);
    b0.v = *(const uint4*)(gB);      b1.v = *(const uint4*)(gB + 16);
#define WRT(buf) do {                                              \
        *(long long*)((char*)As[buf] + w0) = a0.q[0];              \
        *(long long*)((char*)As[buf] + w1) = a0.q[1];              \
        *(long long*)((char*)As[buf] + w2) = a1.q[0];              \
        *(long long*)((char*)As[buf] + w3) = a1.q[1];              \
        *(long long*)((char*)Bs[buf] + w0) = b0.q[0];              \
        *(long long*)((char*)Bs[buf] + w1) = b0.q[1];              \
        *(long long*)((char*)Bs[buf] + w2) = b1.q[0];              \
        *(long long*)((char*)Bs[buf] + w3) = b1.q[1];              \
    } while (0)
    WRT(0);
    __syncthreads();

    for (int kt = 0; kt < 4; ++kt) {
        int cur = kt & 1;
        if (kt < 3) {                        // issue next-tile loads early (T14)
            int ko = (kt + 1) * 128;
            a0.v = *(const uint4*)(gA + ko);  a1.v = *(const uint4*)(gA + ko + 16);
            b0.v = *(const uint4*)(gB + ko);  b1.v = *(const uint4*)(gB + ko + 16);
        }
#pragma unroll
        for (int kh = 0; kh < 4; ++kh) {
            int ck = ((kh * 32) | g8) ^ sK;
            long long af[4], bf[4];
#pragma unroll
            for (int mi = 0; mi < 4; ++mi)
                af[mi] = *(const long long*)((const char*)As[cur] + pA[mi] + ck);
#pragma unroll
            for (int ni = 0; ni < 4; ++ni)
                bf[ni] = *(const long long*)((const char*)Bs[cur] + pB[ni] + ck);
#pragma unroll
            for (int mi = 0; mi < 4; ++mi)
#pragma unroll
                for (int ni = 0; ni < 4; ++ni)
                    acc[mi][ni] = __builtin_amdgcn_mfma_f32_16x16x32_fp8_fp8(
                        af[mi], bf[ni], acc[mi][ni], 0, 0, 0);
        }
        if (kt < 3) WRT(cur ^ 1);            // write staged tile to other buffer
        __syncthreads();                     // single barrier per K-iter
    }
#undef WRT

    // epilogue: exp + per-token partial sums over this wave's 64 vocab cols
    float esum[4][4];   // [mi][r]
#pragma unroll
    for (int mi = 0; mi < 4; ++mi)
#pragma unroll
        for (int r = 0; r < 4; ++r) esum[mi][r] = 0.f;
#pragma unroll
    for (int ni = 0; ni < 4; ++ni) {
        int v = n0 + wc * 64 + ni * 16 + (lane & 15);
        bool ok = v < VOCAB;
        float bo = ok ? b_out[v] : 0.f;
#pragma unroll
        for (int mi = 0; mi < 4; ++mi)
#pragma unroll
            for (int r = 0; r < 4; ++r) {
                float logit = acc[mi][ni][r] + bo;
                esum[mi][r] += ok ? __expf(logit) : 0.f;
            }
    }
#pragma unroll
    for (int d = 1; d < 16; d <<= 1)
#pragma unroll
        for (int mi = 0; mi < 4; ++mi)
#pragma unroll
            for (int r = 0; r < 4; ++r) esum[mi][r] += __shfl_xor(esum[mi][r], d, 64);
    if ((lane & 15) == 0) {
#pragma unroll
        for (int mi = 0; mi < 4; ++mi)
#pragma unroll
            for (int r = 0; r < 4; ++r) {
                int tok = m0 + wr * 64 + mi * 16 + (lane >> 4) * 4 + r;
                partial[(size_t)tok * 512 + nb * 4 + wc] = esum[mi][r];
            }
    }
}

// ---------------- fused: lse reduce + target logit (one wave per token) ----------------
__global__ void k_lse_tlg(const float* __restrict__ partial,
                          const unsigned char* __restrict__ HS8,
                          const unsigned char* __restrict__ W8,
                          const float* __restrict__ b_out,
                          const int* __restrict__ target,
                          float* __restrict__ lse, float* __restrict__ tlg) {
    int tok = blockIdx.x * 4 + (threadIdx.x >> 6);
    int lane = threadIdx.x & 63;
    int tg = target[tok];
    uint2 ha = *(const uint2*)(HS8 + (size_t)tok * DIM + lane * 8);
    uint2 wa = *(const uint2*)(W8 + (size_t)tg * DIM + lane * 8);
    float s = 0.f;
#pragma unroll
    for (int i = 0; i < 4; ++i)
        s += e4m32f((ha.x >> (8 * i)) & 0xFF) * e4m32f((wa.x >> (8 * i)) & 0xFF);
#pragma unroll
    for (int i = 0; i < 4; ++i)
        s += e4m32f((ha.y >> (8 * i)) & 0xFF) * e4m32f((wa.y >> (8 * i)) & 0xFF);
    float s2 = 0.f;
    for (int j = lane; j < NVC; j += 64) s2 += partial[(size_t)tok * 512 + j];
#pragma unroll
    for (int d = 1; d < 64; d <<= 1) {
        s  += __shfl_xor(s, d, 64);
        s2 += __shfl_xor(s2, d, 64);
    }
    if (lane == 0) {
        tlg[tok] = s + b_out[tg];
        lse[tok] = logf(s2);
    }
}

// ---------------- loss + masked mean ----------------
__global__ void k_finalize(const float* __restrict__ lse, const float* __restrict__ tlg,
                           const int* __restrict__ target, float* __restrict__ out) {
    __shared__ float ssum[256];
    __shared__ float scnt[256];
    int t = threadIdx.x;
    float ls = 0.f, lc = 0.f;
    for (int i = t; i < TOKENS; i += 256) {
        int tg = target[i];
        float loss = (tg != 0) ? (lse[i] - tlg[i]) : 0.f;
        out[i] = loss;
        ls += loss;
        lc += (tg != 0) ? 1.f : 0.f;
    }
    ssum[t] = ls; scnt[t] = lc;
    __syncthreads();
    for (int d = 128; d > 0; d >>= 1) {
        if (t < d) { ssum[t] += ssum[t + d]; scnt[t] += scnt[t + d]; }
        __syncthreads();
    }
    if (t == 0) out[TOKENS] = ssum[0] / fmaxf(scnt[0], 1.f);
}

extern "C" void kernel_launch(void* const* d_in, const int* in_sizes, int n_in,
                              void* d_out, int out_size, void* d_ws, size_t ws_size,
                              hipStream_t stream) {
    const int*   review_input  = (const int*)d_in[2];
    const int*   review_target = (const int*)d_in[3];
    const float* word_emb      = (const float*)d_in[4];
    const float* W_ih          = (const float*)d_in[5];
    const float* W_hh          = (const float*)d_in[6];
    const float* b_ih          = (const float*)d_in[7];
    const float* b_hh          = (const float*)d_in[8];
    const float* W_out         = (const float*)d_in[9];
    const float* b_out         = (const float*)d_in[10];
    float* out = (float*)d_out;

    char* ws = (char*)d_ws;
    size_t off = 0;
    auto alloc = [&](size_t n) { char* p = ws + off; off += (n + 255) & ~(size_t)255; return p; };
    unsigned short* Xb    = (unsigned short*)alloc((size_t)TOKENS * DIM * 2);
    unsigned short* Wihb  = (unsigned short*)alloc((size_t)G3 * DIM * 2);
    unsigned short* Whhb  = (unsigned short*)alloc((size_t)G3 * HID * 2);
    unsigned char*  Wout8 = (unsigned char*)alloc((size_t)VOCAB * DIM);
    unsigned short* HS    = (unsigned short*)alloc((size_t)TOKENS * HID * 2);
    unsigned char*  HS8   = (unsigned char*)alloc((size_t)TOKENS * HID);
    unsigned short* hzero = (unsigned short*)alloc((size_t)BATCH * HID * 2);
    float* hf      = (float*)alloc((size_t)BATCH * HID * 4);
    float* GI      = (float*)alloc((size_t)TOKENS * G3 * 4);
    float* partial = (float*)alloc((size_t)TOKENS * 512 * 4);
    float* lse     = (float*)alloc((size_t)TOKENS * 4);
    float* tlg     = (float*)alloc((size_t)TOKENS * 4);
    (void)ws_size; (void)in_sizes; (void)n_in; (void)out_size;

    // weight conversions + embedding gather
    k_cvt_bf16<<<dim3((G3 * DIM / 8 + 255) / 256), dim3(256), 0, stream>>>(W_ih, Wihb, G3 * DIM / 8);
    k_cvt_bf16<<<dim3((G3 * HID / 8 + 255) / 256), dim3(256), 0, stream>>>(W_hh, Whhb, G3 * HID / 8);
    k_cvt_fp8<<<dim3((VOCAB * DIM / 16 + 255) / 256), dim3(256), 0, stream>>>(W_out, Wout8, VOCAB * DIM / 16);
    k_gather_x<<<dim3(TOKENS * DIM / 8 / 256), dim3(256), 0, stream>>>(word_emb, review_input, Xb);

    // GI = X @ W_ih^T + b_ih
    k_gemm_gi<<<dim3(TOKENS / 64, G3 / 64), dim3(256), 0, stream>>>(Xb, Wihb, b_ih, GI);

    // GRU recurrence: 50 per-step kernels, 256 blocks x 64 thr (all CUs);
    // fp8 h written inline (no separate conversion pass)
    hipMemsetAsync(hf, 0, (size_t)BATCH * HID * 4, stream);
    hipMemsetAsync(hzero, 0, (size_t)BATCH * HID * 2, stream);
    for (int s = 0; s < S_LEN; ++s) {
        const unsigned short* hin = s ? (HS + (size_t)(s - 1) * BATCH * HID) : hzero;
        unsigned short* hout = HS + (size_t)s * BATCH * HID;
        unsigned char*  hout8 = HS8 + (size_t)s * BATCH * HID;
        k_gru_step<<<dim3(256), dim3(64), 0, stream>>>(GI, Whhb, b_hh, hf, hin, hout, hout8, s);
    }

    // decode: partial exp-sums, fused lse+tlogit, final loss
    k_decode<<<dim3(NWG), dim3(1024), 0, stream>>>(HS8, Wout8, b_out, partial);
    k_lse_tlg<<<dim3(TOKENS / 4), dim3(256), 0, stream>>>(partial, HS8, Wout8, b_out, review_target, lse, tlg);
    k_finalize<<<dim3(1), dim3(256), 0, stream>>>(lse, tlg, review_target, out);
}